// Round 1
// baseline (312.441 us; speedup 1.0000x reference)
//
#include <hip/hip_runtime.h>

// GCN link predictor. fp32 math, bf16 intermediates + bf16 MFMA GEMM.
// Pipeline: block-hist -> s1 -> stage[+inline bucket-base scan] -> FUSED[scatter+gemm1] ->
//           agg1 x4 col-passes -> gemm2 -> agg2 x4 -> decode x4.   (17 dispatches)
// norm factorization: h'[i] = dinv[i]*(x@W)[i];  z[i] = dinv[i]*(h'[i] + sum_{src->i} h'[src]) + b.
// R5: MFMA GEMM. R6 FAILED: hot global atomics. R7: deterministic-offset bucket CSR. R8: 248us.
// R9 FAILED: grid.sync ~60us/ea. R10: quarter-wave gathers (neutral; gathers at random-access
// floor). R11 FAILED: agg1+gemm2 fusion cut gather parallelism 4x. R12: fuse scatter+gemm1.
// R13: column-pass blocking for gathers. The 4.5 TB/s "gather floor" was an L2-capacity
// artifact: H/Z = 12.8 MB > 4 MiB per-XCD L2 -> ~69% of gather lines missed to LLC. A
// 32-column slice touches exactly one 64B line per row (row-major layout), working set
// N*64B = 3.2 MB < 4 MiB. Split agg/decode into 4 column passes as SEPARATE dispatches
// (stream order = temporal L2 partitioning; 4-lane group per node, uint4/lane). Decode
// accumulates partial dots into out (pass0 writes, pass1-3 RMW, stream-ordered).

typedef __attribute__((ext_vector_type(8))) short short8;   // 8 bf16 (A/B frag)
typedef __attribute__((ext_vector_type(4))) float floatx4;  // C/D frag

#define STAGE_G 128   // staging blocks

__device__ __forceinline__ unsigned short f2bf(float f) {
    union { float f; unsigned int u; } v; v.f = f;
    unsigned int u = v.u;
    u += 0x7fffu + ((u >> 16) & 1u);   // round-to-nearest-even
    return (unsigned short)(u >> 16);
}

__device__ __forceinline__ unsigned int pack2(float a, float b) {
    return (unsigned int)f2bf(a) | ((unsigned int)f2bf(b) << 16);
}

__device__ __forceinline__ float4 cvt4(unsigned int lo, unsigned int hi) {
    float4 f;
    f.x = __uint_as_float(lo << 16);
    f.y = __uint_as_float(lo & 0xffff0000u);
    f.z = __uint_as_float(hi << 16);
    f.w = __uint_as_float(hi & 0xffff0000u);
    return f;
}

// --- CSR build ---

__global__ __launch_bounds__(256) void block_hist_kernel(const int* __restrict__ dst,
                                                         int* __restrict__ bhist,
                                                         int E, int NB) {
    __shared__ int bh[1024];
    int t = threadIdx.x, g = blockIdx.x;
    for (int b = t; b < NB; b += 256) bh[b] = 0;
    __syncthreads();
    int chunk = (E + gridDim.x - 1) / gridDim.x;
    int lo = g * chunk, hi = min(lo + chunk, E);
    for (int i = lo + t; i < hi; i += 256) atomicAdd(&bh[dst[i] >> 6], 1);
    __syncthreads();
    for (int b = t; b < NB; b += 256) bhist[g * NB + b] = bh[b];
}

__global__ __launch_bounds__(128) void s1_scan_blocks(int* __restrict__ bhist,
                                                      int* __restrict__ T, int NB) {
    __shared__ int s[2][128];
    int b = blockIdx.x, t = threadIdx.x;
    int v = bhist[t * NB + b];
    int cur = 0;
    s[0][t] = v;
    __syncthreads();
#pragma unroll
    for (int off = 1; off < 128; off <<= 1) {
        int nxt = cur ^ 1;
        int val = s[cur][t];
        if (t >= off) val += s[cur][t - off];
        s[nxt][t] = val;
        __syncthreads();
        cur = nxt;
    }
    int inc = s[cur][t];
    bhist[t * NB + b] = inc - v;       // exclusive over blocks
    if (t == 127) T[b] = inc;
}

// Stage with inline bucket-base scan: each block redundantly exclusive-scans T[NB]
// (4 buckets/thread); block 0 also emits global bucket_base.
__global__ __launch_bounds__(256) void stage_kernel(const int* __restrict__ src,
                                                    const int* __restrict__ dst,
                                                    const int* __restrict__ bhist,
                                                    const int* __restrict__ T,
                                                    int* __restrict__ bucket_base,
                                                    unsigned int* __restrict__ stage,
                                                    int E, int NB) {
    __shared__ int lcur[1024];
    __shared__ int sb[2][256];
    int t = threadIdx.x, g = blockIdx.x;

    int b0 = t * 4;
    int v[4];
    int s = 0;
#pragma unroll
    for (int i = 0; i < 4; ++i) {
        int b = b0 + i;
        v[i] = (b < NB) ? T[b] : 0;
        s += v[i];
    }
    int cur = 0;
    sb[0][t] = s;
    __syncthreads();
#pragma unroll
    for (int off = 1; off < 256; off <<= 1) {
        int val = sb[cur][t];
        if (t >= off) val += sb[cur][t - off];
        sb[cur ^ 1][t] = val;
        __syncthreads();
        cur ^= 1;
    }
    int run = sb[cur][t] - s;   // exclusive base for bucket b0
#pragma unroll
    for (int i = 0; i < 4; ++i) {
        int b = b0 + i;
        if (b < NB) {
            lcur[b] = run + bhist[(size_t)g * NB + b];
            if (g == 0) bucket_base[b] = run;
        }
        run += v[i];
    }
    if (g == 0 && t == 255) bucket_base[NB] = run;   // == E
    __syncthreads();

    int chunk = (E + gridDim.x - 1) / gridDim.x;
    int lo = g * chunk, hi = min(lo + chunk, E);
    for (int i = lo + t; i < hi; i += 256) {
        int d = dst[i];
        int pos = atomicAdd(&lcur[d >> 6], 1);
        stage[pos] = ((unsigned int)src[i] << 6) | (unsigned int)(d & 63);
    }
}

// --- FUSED scatter + layer-1 GEMM. One block per bucket b == one 64-row gemm tile.
__global__ __launch_bounds__(256) void scatter_gemm_kernel(const unsigned int* __restrict__ stage,
                                                           const int* __restrict__ bucket_base,
                                                           int* __restrict__ row_ptr,
                                                           float* __restrict__ dinv,
                                                           int* __restrict__ srcs_sorted,
                                                           const float* __restrict__ Xv,
                                                           const float* __restrict__ W,
                                                           uint2* __restrict__ H, int N) {
    __shared__ __align__(16) char smem[50176];
    __shared__ int cnt[64];
    __shared__ int lcur[64];
    __shared__ float sdinv[64];
    short* WB = (short*)smem;            // [nt][kt][lane][j]
    short* XL = (short*)(smem + 32768);  // [row][k], row stride 136 shorts
    float* Cst = (float*)smem;           // epilogue overlay: [row][col], stride 132 floats

    const int tid = threadIdx.x;
    const int blk = blockIdx.x;

    // ---- Phase 1: scatter bucket blk ----
    {
        int t = tid;
        int lo = blk << 6;
        int base = bucket_base[blk], basen = bucket_base[blk + 1];
        if (t < 64) cnt[t] = 0;
        __syncthreads();
        for (int i = base + t; i < basen; i += 256) atomicAdd(&cnt[stage[i] & 63u], 1);
        __syncthreads();
        if (t < 64) {
            int v = cnt[t];
            int inc = v;
#pragma unroll
            for (int off = 1; off < 64; off <<= 1) {
                int x = __shfl_up(inc, off, 64);
                if (t >= off) inc += x;
            }
            int exc = inc - v;
            int node = lo + t;
            float di = rsqrtf((float)(v + 1));   // +1 self-loop
            if (node < N) {
                row_ptr[node] = base + exc;
                dinv[node] = di;
                if (node == N - 1) row_ptr[N] = base + exc + v;
                sdinv[t] = di;
            } else {
                sdinv[t] = 0.f;
            }
            lcur[t] = base + exc;
        }
        __syncthreads();
        for (int i = base + t; i < basen; i += 256) {
            unsigned int rec = stage[i];
            int pos = atomicAdd(&lcur[rec & 63u], 1);
            srcs_sorted[pos] = (int)(rec >> 6);
        }
    }
    __syncthreads();

    // ---- Phase 2: gemm1 (fp32 X @ W -> bf16 H, dinv from LDS) ----
    {
        const float4* W4 = (const float4*)W;
#pragma unroll
        for (int i = 0; i < 16; ++i) {
            int f = tid + i * 256;
            int k = f >> 5;
            int c4 = f & 31;
            float4 wv = W4[f];
            int kt = k >> 5, q = (k >> 3) & 3, j = k & 7;
            float e[4] = {wv.x, wv.y, wv.z, wv.w};
#pragma unroll
            for (int m = 0; m < 4; ++m) {
                int c = c4 * 4 + m;
                int nt = c >> 4;
                int ln = q * 16 + (c & 15);
                WB[((nt * 4 + kt) * 64 + ln) * 8 + j] = (short)f2bf(e[m]);
            }
        }
    }
    {
#pragma unroll
        for (int i = 0; i < 8; ++i) {
            int f = tid + i * 256;
            int row = f >> 5;
            int c4 = f & 31;
            int gr = min(blk * 64 + row, N - 1);
            float4 xv = ((const float4*)Xv)[(size_t)gr * 32 + c4];
            uint2 u;
            u.x = pack2(xv.x, xv.y);
            u.y = pack2(xv.z, xv.w);
            *(uint2*)&XL[row * 136 + c4 * 4] = u;
        }
    }
    __syncthreads();

    const int w = tid >> 6;
    const int lane = tid & 63;
    const int arow = w * 16 + (lane & 15);
    const int koff = (lane >> 4) * 8;
    short8 a[4];
#pragma unroll
    for (int kt = 0; kt < 4; ++kt)
        a[kt] = *(const short8*)&XL[arow * 136 + kt * 32 + koff];

    floatx4 acc[8];
#pragma unroll
    for (int nt = 0; nt < 8; ++nt) acc[nt] = (floatx4){0.f, 0.f, 0.f, 0.f};

#pragma unroll
    for (int kt = 0; kt < 4; ++kt) {
#pragma unroll
        for (int nt = 0; nt < 8; ++nt) {
            short8 b = *(const short8*)&WB[((nt * 4 + kt) * 64 + lane) * 8];
            acc[nt] = __builtin_amdgcn_mfma_f32_16x16x32_bf16(a[kt], b, acc[nt], 0, 0, 0);
        }
    }
    __syncthreads();

    {
        int q = lane >> 4, cn = lane & 15;
#pragma unroll
        for (int nt = 0; nt < 8; ++nt)
#pragma unroll
            for (int r = 0; r < 4; ++r)
                Cst[(w * 16 + q * 4 + r) * 132 + nt * 16 + cn] = acc[nt][r];
    }
    __syncthreads();
    {
#pragma unroll
        for (int i = 0; i < 8; ++i) {
            int f = tid + i * 256;
            int row = f >> 5;
            int c4 = f & 31;
            int gr = blk * 64 + row;
            if (gr < N) {
                float4 v = *(float4*)&Cst[row * 132 + c4 * 4];
                float di = sdinv[row];
                uint2 o;
                o.x = pack2(v.x * di, v.y * di);
                o.y = pack2(v.z * di, v.w * di);
                H[(size_t)gr * 32 + c4] = o;
            }
        }
    }
}

// --- standalone MFMA GEMM (layer 2, bf16 input) ---
__global__ __launch_bounds__(256) void gemm_mfma_kernel(const unsigned short* __restrict__ Xv,
                                                        const float* __restrict__ W,
                                                        const float* __restrict__ dinv,
                                                        uint2* __restrict__ H, int N) {
    __shared__ __align__(16) char smem[50176];
    short* WB = (short*)smem;
    short* XL = (short*)(smem + 32768);
    float* Cst = (float*)smem;

    const int tid = threadIdx.x;
    const int w = tid >> 6;
    const int lane = tid & 63;
    const int blk = blockIdx.x;

    {
        const float4* W4 = (const float4*)W;
#pragma unroll
        for (int i = 0; i < 16; ++i) {
            int f = tid + i * 256;
            int k = f >> 5;
            int c4 = f & 31;
            float4 wv = W4[f];
            int kt = k >> 5, q = (k >> 3) & 3, j = k & 7;
            float e[4] = {wv.x, wv.y, wv.z, wv.w};
#pragma unroll
            for (int m = 0; m < 4; ++m) {
                int c = c4 * 4 + m;
                int nt = c >> 4;
                int ln = q * 16 + (c & 15);
                WB[((nt * 4 + kt) * 64 + ln) * 8 + j] = (short)f2bf(e[m]);
            }
        }
    }
    {
#pragma unroll
        for (int i = 0; i < 8; ++i) {
            int f = tid + i * 256;
            int row = f >> 5;
            int c4 = f & 31;
            int gr = min(blk * 64 + row, N - 1);
            uint2 u = ((const uint2*)Xv)[(size_t)gr * 32 + c4];
            *(uint2*)&XL[row * 136 + c4 * 4] = u;
        }
    }
    __syncthreads();

    const int arow = w * 16 + (lane & 15);
    const int koff = (lane >> 4) * 8;
    short8 a[4];
#pragma unroll
    for (int kt = 0; kt < 4; ++kt)
        a[kt] = *(const short8*)&XL[arow * 136 + kt * 32 + koff];

    floatx4 acc[8];
#pragma unroll
    for (int nt = 0; nt < 8; ++nt) acc[nt] = (floatx4){0.f, 0.f, 0.f, 0.f};

#pragma unroll
    for (int kt = 0; kt < 4; ++kt) {
#pragma unroll
        for (int nt = 0; nt < 8; ++nt) {
            short8 b = *(const short8*)&WB[((nt * 4 + kt) * 64 + lane) * 8];
            acc[nt] = __builtin_amdgcn_mfma_f32_16x16x32_bf16(a[kt], b, acc[nt], 0, 0, 0);
        }
    }
    __syncthreads();

    {
        int q = lane >> 4, cn = lane & 15;
#pragma unroll
        for (int nt = 0; nt < 8; ++nt)
#pragma unroll
            for (int r = 0; r < 4; ++r)
                Cst[(w * 16 + q * 4 + r) * 132 + nt * 16 + cn] = acc[nt][r];
    }
    __syncthreads();
    {
#pragma unroll
        for (int i = 0; i < 8; ++i) {
            int f = tid + i * 256;
            int row = f >> 5;
            int c4 = f & 31;
            int gr = blk * 64 + row;
            if (gr < N) {
                float4 v = *(float4*)&Cst[row * 132 + c4 * 4];
                float di = dinv[gr];
                uint2 o;
                o.x = pack2(v.x * di, v.y * di);
                o.y = pack2(v.z * di, v.w * di);
                H[(size_t)gr * 32 + c4] = o;
            }
        }
    }
}

// R13 agg: one 32-column pass. 4-lane group per node (16 nodes/wave); lane sl holds 8
// cols (uint4) at column offset pass*4+sl. Gather working set per pass = N*64B = 3.2MB
// (one 64B line per row) -> per-XCD-L2 resident. fp32 accumulate, same per-column
// summation order as the old quarter-wave kernel.
__global__ __launch_bounds__(256) void agg_pass_kernel(const unsigned short* __restrict__ Hp,
                                                       const int* __restrict__ row_ptr,
                                                       const int* __restrict__ srcs,
                                                       const float* __restrict__ dinv,
                                                       const float* __restrict__ bias,
                                                       unsigned short* __restrict__ Z,
                                                       int N, int do_relu, int pass) {
    int n = (int)((blockIdx.x * blockDim.x + threadIdx.x) >> 2);
    int sl = threadIdx.x & 3;
    if (n >= N) return;
    const uint4* H4 = (const uint4*)Hp;
    const int co = pass * 4 + sl;   // uint4 column offset within 16-uint4 row

    uint4 us = H4[(size_t)n * 16 + co];          // self term (h'[n])
    float4 a0 = cvt4(us.x, us.y);
    float4 a1 = cvt4(us.z, us.w);
    float4 b0 = make_float4(0.f, 0.f, 0.f, 0.f);
    float4 b1 = make_float4(0.f, 0.f, 0.f, 0.f);

    int j = row_ptr[n], end = row_ptr[n + 1];
    for (; j + 7 < end; j += 8) {
        uint4 u0 = H4[(size_t)srcs[j + 0] * 16 + co];
        uint4 u1 = H4[(size_t)srcs[j + 1] * 16 + co];
        uint4 u2 = H4[(size_t)srcs[j + 2] * 16 + co];
        uint4 u3 = H4[(size_t)srcs[j + 3] * 16 + co];
        uint4 u4 = H4[(size_t)srcs[j + 4] * 16 + co];
        uint4 u5 = H4[(size_t)srcs[j + 5] * 16 + co];
        uint4 u6 = H4[(size_t)srcs[j + 6] * 16 + co];
        uint4 u7 = H4[(size_t)srcs[j + 7] * 16 + co];
        float4 t;
        t = cvt4(u0.x, u0.y); a0.x += t.x; a0.y += t.y; a0.z += t.z; a0.w += t.w;
        t = cvt4(u0.z, u0.w); a1.x += t.x; a1.y += t.y; a1.z += t.z; a1.w += t.w;
        t = cvt4(u1.x, u1.y); b0.x += t.x; b0.y += t.y; b0.z += t.z; b0.w += t.w;
        t = cvt4(u1.z, u1.w); b1.x += t.x; b1.y += t.y; b1.z += t.z; b1.w += t.w;
        t = cvt4(u2.x, u2.y); a0.x += t.x; a0.y += t.y; a0.z += t.z; a0.w += t.w;
        t = cvt4(u2.z, u2.w); a1.x += t.x; a1.y += t.y; a1.z += t.z; a1.w += t.w;
        t = cvt4(u3.x, u3.y); b0.x += t.x; b0.y += t.y; b0.z += t.z; b0.w += t.w;
        t = cvt4(u3.z, u3.w); b1.x += t.x; b1.y += t.y; b1.z += t.z; b1.w += t.w;
        t = cvt4(u4.x, u4.y); a0.x += t.x; a0.y += t.y; a0.z += t.z; a0.w += t.w;
        t = cvt4(u4.z, u4.w); a1.x += t.x; a1.y += t.y; a1.z += t.z; a1.w += t.w;
        t = cvt4(u5.x, u5.y); b0.x += t.x; b0.y += t.y; b0.z += t.z; b0.w += t.w;
        t = cvt4(u5.z, u5.w); b1.x += t.x; b1.y += t.y; b1.z += t.z; b1.w += t.w;
        t = cvt4(u6.x, u6.y); a0.x += t.x; a0.y += t.y; a0.z += t.z; a0.w += t.w;
        t = cvt4(u6.z, u6.w); a1.x += t.x; a1.y += t.y; a1.z += t.z; a1.w += t.w;
        t = cvt4(u7.x, u7.y); b0.x += t.x; b0.y += t.y; b0.z += t.z; b0.w += t.w;
        t = cvt4(u7.z, u7.w); b1.x += t.x; b1.y += t.y; b1.z += t.z; b1.w += t.w;
    }
    for (; j + 3 < end; j += 4) {
        uint4 u0 = H4[(size_t)srcs[j + 0] * 16 + co];
        uint4 u1 = H4[(size_t)srcs[j + 1] * 16 + co];
        uint4 u2 = H4[(size_t)srcs[j + 2] * 16 + co];
        uint4 u3 = H4[(size_t)srcs[j + 3] * 16 + co];
        float4 t;
        t = cvt4(u0.x, u0.y); a0.x += t.x; a0.y += t.y; a0.z += t.z; a0.w += t.w;
        t = cvt4(u0.z, u0.w); a1.x += t.x; a1.y += t.y; a1.z += t.z; a1.w += t.w;
        t = cvt4(u1.x, u1.y); b0.x += t.x; b0.y += t.y; b0.z += t.z; b0.w += t.w;
        t = cvt4(u1.z, u1.w); b1.x += t.x; b1.y += t.y; b1.z += t.z; b1.w += t.w;
        t = cvt4(u2.x, u2.y); a0.x += t.x; a0.y += t.y; a0.z += t.z; a0.w += t.w;
        t = cvt4(u2.z, u2.w); a1.x += t.x; a1.y += t.y; a1.z += t.z; a1.w += t.w;
        t = cvt4(u3.x, u3.y); b0.x += t.x; b0.y += t.y; b0.z += t.z; b0.w += t.w;
        t = cvt4(u3.z, u3.w); b1.x += t.x; b1.y += t.y; b1.z += t.z; b1.w += t.w;
    }
    for (; j < end; ++j) {
        uint4 u = H4[(size_t)srcs[j] * 16 + co];
        float4 t;
        t = cvt4(u.x, u.y); a0.x += t.x; a0.y += t.y; a0.z += t.z; a0.w += t.w;
        t = cvt4(u.z, u.w); a1.x += t.x; a1.y += t.y; a1.z += t.z; a1.w += t.w;
    }
    a0.x += b0.x; a0.y += b0.y; a0.z += b0.z; a0.w += b0.w;
    a1.x += b1.x; a1.y += b1.y; a1.z += b1.z; a1.w += b1.w;

    float di = dinv[n];
    float4 bv0 = ((const float4*)bias)[2 * co];
    float4 bv1 = ((const float4*)bias)[2 * co + 1];
    float o0 = di * a0.x + bv0.x, o1 = di * a0.y + bv0.y;
    float o2 = di * a0.z + bv0.z, o3 = di * a0.w + bv0.w;
    float o4 = di * a1.x + bv1.x, o5 = di * a1.y + bv1.y;
    float o6 = di * a1.z + bv1.z, o7 = di * a1.w + bv1.w;
    if (do_relu) {
        o0 = fmaxf(o0, 0.f); o1 = fmaxf(o1, 0.f); o2 = fmaxf(o2, 0.f); o3 = fmaxf(o3, 0.f);
        o4 = fmaxf(o4, 0.f); o5 = fmaxf(o5, 0.f); o6 = fmaxf(o6, 0.f); o7 = fmaxf(o7, 0.f);
    }
    uint4 o;
    o.x = pack2(o0, o1);
    o.y = pack2(o2, o3);
    o.z = pack2(o4, o5);
    o.w = pack2(o6, o7);
    ((uint4*)Z)[(size_t)n * 16 + co] = o;
}

// R13 decode: one 32-column pass; 4-lane group per pair, partial dot accumulated into
// out across the 4 stream-ordered pass dispatches (pass0 writes, pass1-3 RMW).
__global__ __launch_bounds__(256) void decode_pass_kernel(const unsigned short* __restrict__ Zp,
                                                          const int* __restrict__ pa,
                                                          const int* __restrict__ pb,
                                                          float* __restrict__ out,
                                                          int P, int pass) {
    int pr = (int)((blockIdx.x * blockDim.x + threadIdx.x) >> 2);
    int sl = threadIdx.x & 3;
    if (pr >= P) return;
    const uint4* Z4 = (const uint4*)Zp;
    const int co = pass * 4 + sl;

    int A = pa[pr], B = pb[pr];
    uint4 ua = Z4[(size_t)A * 16 + co];
    uint4 ub = Z4[(size_t)B * 16 + co];

    float4 xa = cvt4(ua.x, ua.y), ya = cvt4(ua.z, ua.w);
    float4 xb = cvt4(ub.x, ub.y), yb = cvt4(ub.z, ub.w);
    float v = xa.x * xb.x + xa.y * xb.y + xa.z * xb.z + xa.w * xb.w
            + ya.x * yb.x + ya.y * yb.y + ya.z * yb.z + ya.w * yb.w;
    v += __shfl_xor(v, 1, 4);
    v += __shfl_xor(v, 2, 4);
    if (sl == 0) {
        if (pass == 0) out[pr] = v;
        else out[pr] += v;
    }
}

extern "C" void kernel_launch(void* const* d_in, const int* in_sizes, int n_in,
                              void* d_out, int out_size, void* d_ws, size_t ws_size,
                              hipStream_t stream) {
    const int*   edge_index = (const int*)d_in[0];
    const int*   edge_pairs = (const int*)d_in[1];
    const float* emb        = (const float*)d_in[2];
    const float* W1         = (const float*)d_in[3];
    const float* b1         = (const float*)d_in[4];
    const float* W2         = (const float*)d_in[5];
    const float* b2         = (const float*)d_in[6];
    float* out = (float*)d_out;

    int E = in_sizes[0] / 2;
    int P = in_sizes[1] / 2;
    int N = in_sizes[2] / 128;
    int NB = (N + 63) / 64;    // buckets == gemm tiles (782 for N=50000; must be <= 1024)

    const int* src = edge_index;
    const int* dst = edge_index + E;
    const int* pa  = edge_pairs;
    const int* pb  = edge_pairs + P;

    char* ws = (char*)d_ws;
    size_t off = 0;
    auto alloc = [&](size_t bytes) -> void* {
        void* p = ws + off;
        off = (off + bytes + 255) & ~(size_t)255;
        return p;
    };
    unsigned short* bufA = (unsigned short*)alloc((size_t)N * 128 * 2); // h1' then h2'
    unsigned short* bufB = (unsigned short*)alloc((size_t)N * 128 * 2); // z1 then z2
    int*   srcs_sorted  = (int*)alloc((size_t)E * sizeof(int));
    unsigned int* stage = (unsigned int*)alloc((size_t)E * sizeof(unsigned int));
    int*   row_ptr      = (int*)alloc((size_t)(N + 1) * sizeof(int));
    float* dinv         = (float*)alloc((size_t)N * sizeof(float));
    int*   bhist        = (int*)alloc((size_t)STAGE_G * NB * sizeof(int));
    int*   T            = (int*)alloc((size_t)NB * sizeof(int));
    int*   bucket_base  = (int*)alloc((size_t)(NB + 1) * sizeof(int));

    // CSR build front half (3 dispatches)
    block_hist_kernel<<<STAGE_G, 256, 0, stream>>>(dst, bhist, E, NB);
    s1_scan_blocks<<<NB, 128, 0, stream>>>(bhist, T, NB);
    stage_kernel<<<STAGE_G, 256, 0, stream>>>(src, dst, bhist, T, bucket_base, stage, E, NB);

    // FUSED scatter + gemm1: CSR finalize + h1' = dinv*(emb@W1) -> bufA
    scatter_gemm_kernel<<<NB, 256, 0, stream>>>(stage, bucket_base, row_ptr, dinv,
                                                srcs_sorted, emb, W1, (uint2*)bufA, N);

    int aggB = (N + 63) / 64;    // 64 nodes per 256-thread block (4-lane groups)
    int decB = (P + 63) / 64;    // 64 pairs per block

    // agg1: z1 = relu(dinv*(h1'+sum)+b1) -> bufB   (4 column passes, L2-resident slices)
    for (int p = 0; p < 4; ++p)
        agg_pass_kernel<<<aggB, 256, 0, stream>>>(bufA, row_ptr, srcs_sorted, dinv, b1,
                                                  bufB, N, 1, p);

    // gemm2: h2' = dinv*(z1@W2) -> bufA
    gemm_mfma_kernel<<<NB, 256, 0, stream>>>(bufB, W2, dinv, (uint2*)bufA, N);

    // agg2: z2 = dinv*(h2'+sum)+b2 -> bufB   (4 column passes)
    for (int p = 0; p < 4; ++p)
        agg_pass_kernel<<<aggB, 256, 0, stream>>>(bufA, row_ptr, srcs_sorted, dinv, b2,
                                                  bufB, N, 0, p);

    // Decode: 4 column passes, partial dots accumulated into out (stream-ordered)
    for (int p = 0; p < 4; ++p)
        decode_pass_kernel<<<decB, 256, 0, stream>>>(bufB, pa, pb, out, P, p);
}

// Round 2
// 254.193 us; speedup vs baseline: 1.2291x; 1.2291x over previous
//
#include <hip/hip_runtime.h>

// GCN link predictor. fp32 math, bf16 intermediates + bf16 MFMA GEMM.
// Pipeline: block-hist[+Wprepack+pair-hist] -> s1[+pair scan] -> stage[+pair scatter] ->
//           FUSED[scatter+gemm1] -> agg1 -> gemm2 -> agg2 -> decode-bucket.  (8 dispatches)
// norm factorization: h'[i] = dinv[i]*(x@W)[i];  z[i] = dinv[i]*(h'[i] + sum_{src->i} h'[src]) + b.
// R5: MFMA GEMM. R6 FAILED: hot global atomics. R7: deterministic-offset bucket CSR. R8: 248us.
// R9 FAILED: grid.sync ~60us/ea. R10: quarter-wave gathers (neutral). R11 FAILED: agg1+gemm2
// fusion cut gather parallelism. R12: fuse scatter+gemm1 (244.8us). R13 FAILED (312us):
// column-pass blocking -- per-XCD reuse is only E/(8N)=2, so L2-slicing can't beat the
// ~4.5 TB/s LLC random-64B floor; paid 9 dispatch ramps + 4x latency chains for nothing.
// agg1/agg2 are AT the random-gather floor for a random graph -> structural.
// R14: (a) bucket-sort decode pairs by A node (batched into existing CSR dispatches, +0
// launches); decode stages 64 A-rows in LDS -> random gather traffic halves 204.8->102MB.
// (b) one-time W1/W2 prepack into MFMA layout (folded into block_hist blocks 0..31),
// removing 782x redundant per-block f2bf repack from both GEMM kernels.

typedef __attribute__((ext_vector_type(8))) short short8;   // 8 bf16 (A/B frag)
typedef __attribute__((ext_vector_type(4))) float floatx4;  // C/D frag

#define STAGE_G 128   // staging blocks

__device__ __forceinline__ unsigned short f2bf(float f) {
    union { float f; unsigned int u; } v; v.f = f;
    unsigned int u = v.u;
    u += 0x7fffu + ((u >> 16) & 1u);   // round-to-nearest-even
    return (unsigned short)(u >> 16);
}

__device__ __forceinline__ unsigned int pack2(float a, float b) {
    return (unsigned int)f2bf(a) | ((unsigned int)f2bf(b) << 16);
}

__device__ __forceinline__ float4 cvt4(unsigned int lo, unsigned int hi) {
    float4 f;
    f.x = __uint_as_float(lo << 16);
    f.y = __uint_as_float(lo & 0xffff0000u);
    f.z = __uint_as_float(hi << 16);
    f.w = __uint_as_float(hi & 0xffff0000u);
    return f;
}

// --- CSR build (edges + pairs) + W prepack ---

__global__ __launch_bounds__(256) void block_hist_kernel(const int* __restrict__ dst,
                                                         const int* __restrict__ pa,
                                                         int* __restrict__ bhist,
                                                         int* __restrict__ phist,
                                                         const float* __restrict__ W1,
                                                         const float* __restrict__ W2,
                                                         short* __restrict__ wb1,
                                                         short* __restrict__ wb2,
                                                         int E, int P, int NB) {
    __shared__ int bh[1024];
    __shared__ int bh2[1024];
    int t = threadIdx.x, g = blockIdx.x;

    // one-time W prepack into MFMA B layout: WB[((nt*4+kt)*64+ln)*8+j]
    if (g < 32) {
        const float4* W4 = (const float4*)((g < 16) ? W1 : W2);
        short* wb = (g < 16) ? wb1 : wb2;
        int f = ((g & 15) * 256) + t;          // f in [0,4096)
        int k = f >> 5;
        int c4 = f & 31;
        float4 wv = W4[f];
        int kt = k >> 5, q = (k >> 3) & 3, j = k & 7;
        float e[4] = {wv.x, wv.y, wv.z, wv.w};
#pragma unroll
        for (int m = 0; m < 4; ++m) {
            int c = c4 * 4 + m;
            int nt = c >> 4;
            int ln = q * 16 + (c & 15);
            wb[((nt * 4 + kt) * 64 + ln) * 8 + j] = (short)f2bf(e[m]);
        }
    }

    for (int b = t; b < NB; b += 256) { bh[b] = 0; bh2[b] = 0; }
    __syncthreads();
    int chunk = (E + gridDim.x - 1) / gridDim.x;
    int lo = g * chunk, hi = min(lo + chunk, E);
    for (int i = lo + t; i < hi; i += 256) atomicAdd(&bh[dst[i] >> 6], 1);
    int chunkP = (P + gridDim.x - 1) / gridDim.x;
    int loP = g * chunkP, hiP = min(loP + chunkP, P);
    for (int i = loP + t; i < hiP; i += 256) atomicAdd(&bh2[pa[i] >> 6], 1);
    __syncthreads();
    for (int b = t; b < NB; b += 256) {
        bhist[g * NB + b] = bh[b];
        phist[g * NB + b] = bh2[b];
    }
}

__global__ __launch_bounds__(128) void s1_scan_blocks(int* __restrict__ bhist,
                                                      int* __restrict__ phist,
                                                      int* __restrict__ T,
                                                      int* __restrict__ T2, int NB) {
    __shared__ int s[2][128];
    int b = blockIdx.x, t = threadIdx.x;
    // scan edges
    {
        int v = bhist[t * NB + b];
        int cur = 0;
        s[0][t] = v;
        __syncthreads();
#pragma unroll
        for (int off = 1; off < 128; off <<= 1) {
            int nxt = cur ^ 1;
            int val = s[cur][t];
            if (t >= off) val += s[cur][t - off];
            s[nxt][t] = val;
            __syncthreads();
            cur = nxt;
        }
        int inc = s[cur][t];
        bhist[t * NB + b] = inc - v;       // exclusive over blocks
        if (t == 127) T[b] = inc;
        __syncthreads();
    }
    // scan pairs
    {
        int v = phist[t * NB + b];
        int cur = 0;
        s[0][t] = v;
        __syncthreads();
#pragma unroll
        for (int off = 1; off < 128; off <<= 1) {
            int nxt = cur ^ 1;
            int val = s[cur][t];
            if (t >= off) val += s[cur][t - off];
            s[nxt][t] = val;
            __syncthreads();
            cur = nxt;
        }
        int inc = s[cur][t];
        phist[t * NB + b] = inc - v;
        if (t == 127) T2[b] = inc;
    }
}

// Stage with inline bucket-base scans (edges AND pairs): each block redundantly
// exclusive-scans T/T2; block 0 also emits global bucket_base / pair_base.
__global__ __launch_bounds__(256) void stage_kernel(const int* __restrict__ src,
                                                    const int* __restrict__ dst,
                                                    const int* __restrict__ pa,
                                                    const int* __restrict__ bhist,
                                                    const int* __restrict__ phist,
                                                    const int* __restrict__ T,
                                                    const int* __restrict__ T2,
                                                    int* __restrict__ bucket_base,
                                                    int* __restrict__ pair_base,
                                                    unsigned int* __restrict__ stage,
                                                    unsigned int* __restrict__ stageP,
                                                    int E, int P, int NB) {
    __shared__ int lcur[1024];
    __shared__ int lcur2[1024];
    __shared__ int sb[2][256];
    int t = threadIdx.x, g = blockIdx.x;

    int b0 = t * 4;
    // ---- scan 1: edge totals ----
    {
        int v[4];
        int s = 0;
#pragma unroll
        for (int i = 0; i < 4; ++i) {
            int b = b0 + i;
            v[i] = (b < NB) ? T[b] : 0;
            s += v[i];
        }
        int cur = 0;
        sb[0][t] = s;
        __syncthreads();
#pragma unroll
        for (int off = 1; off < 256; off <<= 1) {
            int val = sb[cur][t];
            if (t >= off) val += sb[cur][t - off];
            sb[cur ^ 1][t] = val;
            __syncthreads();
            cur ^= 1;
        }
        int run = sb[cur][t] - s;   // exclusive base for bucket b0
#pragma unroll
        for (int i = 0; i < 4; ++i) {
            int b = b0 + i;
            if (b < NB) {
                lcur[b] = run + bhist[(size_t)g * NB + b];
                if (g == 0) bucket_base[b] = run;
            }
            run += v[i];
        }
        if (g == 0 && t == 255) bucket_base[NB] = run;   // == E
        __syncthreads();
    }
    // ---- scan 2: pair totals ----
    {
        int v[4];
        int s = 0;
#pragma unroll
        for (int i = 0; i < 4; ++i) {
            int b = b0 + i;
            v[i] = (b < NB) ? T2[b] : 0;
            s += v[i];
        }
        int cur = 0;
        sb[0][t] = s;
        __syncthreads();
#pragma unroll
        for (int off = 1; off < 256; off <<= 1) {
            int val = sb[cur][t];
            if (t >= off) val += sb[cur][t - off];
            sb[cur ^ 1][t] = val;
            __syncthreads();
            cur ^= 1;
        }
        int run = sb[cur][t] - s;
#pragma unroll
        for (int i = 0; i < 4; ++i) {
            int b = b0 + i;
            if (b < NB) {
                lcur2[b] = run + phist[(size_t)g * NB + b];
                if (g == 0) pair_base[b] = run;
            }
            run += v[i];
        }
        if (g == 0 && t == 255) pair_base[NB] = run;   // == P
        __syncthreads();
    }

    // scatter edges
    int chunk = (E + gridDim.x - 1) / gridDim.x;
    int lo = g * chunk, hi = min(lo + chunk, E);
    for (int i = lo + t; i < hi; i += 256) {
        int d = dst[i];
        int pos = atomicAdd(&lcur[d >> 6], 1);
        stage[pos] = ((unsigned int)src[i] << 6) | (unsigned int)(d & 63);
    }
    // scatter pairs: rec = (pair_index << 6) | (A & 63); bucket implicit by position
    int chunkP = (P + gridDim.x - 1) / gridDim.x;
    int loP = g * chunkP, hiP = min(loP + chunkP, P);
    for (int i = loP + t; i < hiP; i += 256) {
        int A = pa[i];
        int pos = atomicAdd(&lcur2[A >> 6], 1);
        stageP[pos] = ((unsigned int)i << 6) | (unsigned int)(A & 63);
    }
}

// --- FUSED scatter + layer-1 GEMM. One block per bucket b == one 64-row gemm tile.
__global__ __launch_bounds__(256) void scatter_gemm_kernel(const unsigned int* __restrict__ stage,
                                                           const int* __restrict__ bucket_base,
                                                           int* __restrict__ row_ptr,
                                                           float* __restrict__ dinv,
                                                           int* __restrict__ srcs_sorted,
                                                           const float* __restrict__ Xv,
                                                           const short* __restrict__ wbpre,
                                                           uint2* __restrict__ H, int N) {
    __shared__ __align__(16) char smem[50176];
    __shared__ int cnt[64];
    __shared__ int lcur[64];
    __shared__ float sdinv[64];
    short* WB = (short*)smem;            // [nt][kt][lane][j]
    short* XL = (short*)(smem + 32768);  // [row][k], row stride 136 shorts
    float* Cst = (float*)smem;           // epilogue overlay: [row][col], stride 132 floats

    const int tid = threadIdx.x;
    const int blk = blockIdx.x;

    // ---- Phase 1: scatter bucket blk ----
    {
        int t = tid;
        int lo = blk << 6;
        int base = bucket_base[blk], basen = bucket_base[blk + 1];
        if (t < 64) cnt[t] = 0;
        __syncthreads();
        for (int i = base + t; i < basen; i += 256) atomicAdd(&cnt[stage[i] & 63u], 1);
        __syncthreads();
        if (t < 64) {
            int v = cnt[t];
            int inc = v;
#pragma unroll
            for (int off = 1; off < 64; off <<= 1) {
                int x = __shfl_up(inc, off, 64);
                if (t >= off) inc += x;
            }
            int exc = inc - v;
            int node = lo + t;
            float di = rsqrtf((float)(v + 1));   // +1 self-loop
            if (node < N) {
                row_ptr[node] = base + exc;
                dinv[node] = di;
                if (node == N - 1) row_ptr[N] = base + exc + v;
                sdinv[t] = di;
            } else {
                sdinv[t] = 0.f;
            }
            lcur[t] = base + exc;
        }
        __syncthreads();
        for (int i = base + t; i < basen; i += 256) {
            unsigned int rec = stage[i];
            int pos = atomicAdd(&lcur[rec & 63u], 1);
            srcs_sorted[pos] = (int)(rec >> 6);
        }
    }
    __syncthreads();

    // ---- Phase 2: gemm1 (fp32 X @ W -> bf16 H, dinv from LDS) ----
    {
        // load prepacked W (coalesced uint4 copy)
        const uint4* Wp = (const uint4*)wbpre;
        uint4* WB4 = (uint4*)WB;
#pragma unroll
        for (int i = 0; i < 8; ++i) {
            int idx = tid + i * 256;   // [0,2048)
            WB4[idx] = Wp[idx];
        }
    }
    {
#pragma unroll
        for (int i = 0; i < 8; ++i) {
            int f = tid + i * 256;
            int row = f >> 5;
            int c4 = f & 31;
            int gr = min(blk * 64 + row, N - 1);
            float4 xv = ((const float4*)Xv)[(size_t)gr * 32 + c4];
            uint2 u;
            u.x = pack2(xv.x, xv.y);
            u.y = pack2(xv.z, xv.w);
            *(uint2*)&XL[row * 136 + c4 * 4] = u;
        }
    }
    __syncthreads();

    const int w = tid >> 6;
    const int lane = tid & 63;
    const int arow = w * 16 + (lane & 15);
    const int koff = (lane >> 4) * 8;
    short8 a[4];
#pragma unroll
    for (int kt = 0; kt < 4; ++kt)
        a[kt] = *(const short8*)&XL[arow * 136 + kt * 32 + koff];

    floatx4 acc[8];
#pragma unroll
    for (int nt = 0; nt < 8; ++nt) acc[nt] = (floatx4){0.f, 0.f, 0.f, 0.f};

#pragma unroll
    for (int kt = 0; kt < 4; ++kt) {
#pragma unroll
        for (int nt = 0; nt < 8; ++nt) {
            short8 b = *(const short8*)&WB[((nt * 4 + kt) * 64 + lane) * 8];
            acc[nt] = __builtin_amdgcn_mfma_f32_16x16x32_bf16(a[kt], b, acc[nt], 0, 0, 0);
        }
    }
    __syncthreads();

    {
        int q = lane >> 4, cn = lane & 15;
#pragma unroll
        for (int nt = 0; nt < 8; ++nt)
#pragma unroll
            for (int r = 0; r < 4; ++r)
                Cst[(w * 16 + q * 4 + r) * 132 + nt * 16 + cn] = acc[nt][r];
    }
    __syncthreads();
    {
#pragma unroll
        for (int i = 0; i < 8; ++i) {
            int f = tid + i * 256;
            int row = f >> 5;
            int c4 = f & 31;
            int gr = blk * 64 + row;
            if (gr < N) {
                float4 v = *(float4*)&Cst[row * 132 + c4 * 4];
                float di = sdinv[row];
                uint2 o;
                o.x = pack2(v.x * di, v.y * di);
                o.y = pack2(v.z * di, v.w * di);
                H[(size_t)gr * 32 + c4] = o;
            }
        }
    }
}

// --- standalone MFMA GEMM (layer 2, bf16 input, prepacked W) ---
__global__ __launch_bounds__(256) void gemm_mfma_kernel(const unsigned short* __restrict__ Xv,
                                                        const short* __restrict__ wbpre,
                                                        const float* __restrict__ dinv,
                                                        uint2* __restrict__ H, int N) {
    __shared__ __align__(16) char smem[50176];
    short* WB = (short*)smem;
    short* XL = (short*)(smem + 32768);
    float* Cst = (float*)smem;

    const int tid = threadIdx.x;
    const int w = tid >> 6;
    const int lane = tid & 63;
    const int blk = blockIdx.x;

    {
        const uint4* Wp = (const uint4*)wbpre;
        uint4* WB4 = (uint4*)WB;
#pragma unroll
        for (int i = 0; i < 8; ++i) {
            int idx = tid + i * 256;
            WB4[idx] = Wp[idx];
        }
    }
    {
#pragma unroll
        for (int i = 0; i < 8; ++i) {
            int f = tid + i * 256;
            int row = f >> 5;
            int c4 = f & 31;
            int gr = min(blk * 64 + row, N - 1);
            uint2 u = ((const uint2*)Xv)[(size_t)gr * 32 + c4];
            *(uint2*)&XL[row * 136 + c4 * 4] = u;
        }
    }
    __syncthreads();

    const int arow = w * 16 + (lane & 15);
    const int koff = (lane >> 4) * 8;
    short8 a[4];
#pragma unroll
    for (int kt = 0; kt < 4; ++kt)
        a[kt] = *(const short8*)&XL[arow * 136 + kt * 32 + koff];

    floatx4 acc[8];
#pragma unroll
    for (int nt = 0; nt < 8; ++nt) acc[nt] = (floatx4){0.f, 0.f, 0.f, 0.f};

#pragma unroll
    for (int kt = 0; kt < 4; ++kt) {
#pragma unroll
        for (int nt = 0; nt < 8; ++nt) {
            short8 b = *(const short8*)&WB[((nt * 4 + kt) * 64 + lane) * 8];
            acc[nt] = __builtin_amdgcn_mfma_f32_16x16x32_bf16(a[kt], b, acc[nt], 0, 0, 0);
        }
    }
    __syncthreads();

    {
        int q = lane >> 4, cn = lane & 15;
#pragma unroll
        for (int nt = 0; nt < 8; ++nt)
#pragma unroll
            for (int r = 0; r < 4; ++r)
                Cst[(w * 16 + q * 4 + r) * 132 + nt * 16 + cn] = acc[nt][r];
    }
    __syncthreads();
    {
#pragma unroll
        for (int i = 0; i < 8; ++i) {
            int f = tid + i * 256;
            int row = f >> 5;
            int c4 = f & 31;
            int gr = blk * 64 + row;
            if (gr < N) {
                float4 v = *(float4*)&Cst[row * 132 + c4 * 4];
                float di = dinv[gr];
                uint2 o;
                o.x = pack2(v.x * di, v.y * di);
                o.y = pack2(v.z * di, v.w * di);
                H[(size_t)gr * 32 + c4] = o;
            }
        }
    }
}

// Quarter-wave (16 lanes) per node; lane holds 8 cols as uint4. fp32 accumulate. (R12)
__global__ __launch_bounds__(256) void agg_kernel(const unsigned short* __restrict__ Hp,
                                                  const int* __restrict__ row_ptr,
                                                  const int* __restrict__ srcs,
                                                  const float* __restrict__ dinv,
                                                  const float* __restrict__ bias,
                                                  unsigned short* __restrict__ Z,
                                                  int N, int do_relu) {
    int gw = (int)((blockIdx.x * blockDim.x + threadIdx.x) >> 6);
    int lane = threadIdx.x & 63;
    int q = lane >> 4;
    int hl = lane & 15;
    int n = gw * 4 + q;
    if (n >= N) return;

    const uint4* H4 = (const uint4*)Hp;
    uint4 us = H4[(size_t)n * 16 + hl];
    float4 a0 = cvt4(us.x, us.y);
    float4 a1 = cvt4(us.z, us.w);
    float4 b0 = make_float4(0.f, 0.f, 0.f, 0.f);
    float4 b1 = make_float4(0.f, 0.f, 0.f, 0.f);

    int j = row_ptr[n], end = row_ptr[n + 1];
    for (; j + 7 < end; j += 8) {
        uint4 u0 = H4[(size_t)srcs[j + 0] * 16 + hl];
        uint4 u1 = H4[(size_t)srcs[j + 1] * 16 + hl];
        uint4 u2 = H4[(size_t)srcs[j + 2] * 16 + hl];
        uint4 u3 = H4[(size_t)srcs[j + 3] * 16 + hl];
        uint4 u4 = H4[(size_t)srcs[j + 4] * 16 + hl];
        uint4 u5 = H4[(size_t)srcs[j + 5] * 16 + hl];
        uint4 u6 = H4[(size_t)srcs[j + 6] * 16 + hl];
        uint4 u7 = H4[(size_t)srcs[j + 7] * 16 + hl];
        float4 t;
        t = cvt4(u0.x, u0.y); a0.x += t.x; a0.y += t.y; a0.z += t.z; a0.w += t.w;
        t = cvt4(u0.z, u0.w); a1.x += t.x; a1.y += t.y; a1.z += t.z; a1.w += t.w;
        t = cvt4(u1.x, u1.y); b0.x += t.x; b0.y += t.y; b0.z += t.z; b0.w += t.w;
        t = cvt4(u1.z, u1.w); b1.x += t.x; b1.y += t.y; b1.z += t.z; b1.w += t.w;
        t = cvt4(u2.x, u2.y); a0.x += t.x; a0.y += t.y; a0.z += t.z; a0.w += t.w;
        t = cvt4(u2.z, u2.w); a1.x += t.x; a1.y += t.y; a1.z += t.z; a1.w += t.w;
        t = cvt4(u3.x, u3.y); b0.x += t.x; b0.y += t.y; b0.z += t.z; b0.w += t.w;
        t = cvt4(u3.z, u3.w); b1.x += t.x; b1.y += t.y; b1.z += t.z; b1.w += t.w;
        t = cvt4(u4.x, u4.y); a0.x += t.x; a0.y += t.y; a0.z += t.z; a0.w += t.w;
        t = cvt4(u4.z, u4.w); a1.x += t.x; a1.y += t.y; a1.z += t.z; a1.w += t.w;
        t = cvt4(u5.x, u5.y); b0.x += t.x; b0.y += t.y; b0.z += t.z; b0.w += t.w;
        t = cvt4(u5.z, u5.w); b1.x += t.x; b1.y += t.y; b1.z += t.z; b1.w += t.w;
        t = cvt4(u6.x, u6.y); a0.x += t.x; a0.y += t.y; a0.z += t.z; a0.w += t.w;
        t = cvt4(u6.z, u6.w); a1.x += t.x; a1.y += t.y; a1.z += t.z; a1.w += t.w;
        t = cvt4(u7.x, u7.y); b0.x += t.x; b0.y += t.y; b0.z += t.z; b0.w += t.w;
        t = cvt4(u7.z, u7.w); b1.x += t.x; b1.y += t.y; b1.z += t.z; b1.w += t.w;
    }
    for (; j + 3 < end; j += 4) {
        uint4 u0 = H4[(size_t)srcs[j + 0] * 16 + hl];
        uint4 u1 = H4[(size_t)srcs[j + 1] * 16 + hl];
        uint4 u2 = H4[(size_t)srcs[j + 2] * 16 + hl];
        uint4 u3 = H4[(size_t)srcs[j + 3] * 16 + hl];
        float4 t;
        t = cvt4(u0.x, u0.y); a0.x += t.x; a0.y += t.y; a0.z += t.z; a0.w += t.w;
        t = cvt4(u0.z, u0.w); a1.x += t.x; a1.y += t.y; a1.z += t.z; a1.w += t.w;
        t = cvt4(u1.x, u1.y); b0.x += t.x; b0.y += t.y; b0.z += t.z; b0.w += t.w;
        t = cvt4(u1.z, u1.w); b1.x += t.x; b1.y += t.y; b1.z += t.z; b1.w += t.w;
        t = cvt4(u2.x, u2.y); a0.x += t.x; a0.y += t.y; a0.z += t.z; a0.w += t.w;
        t = cvt4(u2.z, u2.w); a1.x += t.x; a1.y += t.y; a1.z += t.z; a1.w += t.w;
        t = cvt4(u3.x, u3.y); b0.x += t.x; b0.y += t.y; b0.z += t.z; b0.w += t.w;
        t = cvt4(u3.z, u3.w); b1.x += t.x; b1.y += t.y; b1.z += t.z; b1.w += t.w;
    }
    for (; j < end; ++j) {
        uint4 u = H4[(size_t)srcs[j] * 16 + hl];
        float4 t;
        t = cvt4(u.x, u.y); a0.x += t.x; a0.y += t.y; a0.z += t.z; a0.w += t.w;
        t = cvt4(u.z, u.w); a1.x += t.x; a1.y += t.y; a1.z += t.z; a1.w += t.w;
    }
    a0.x += b0.x; a0.y += b0.y; a0.z += b0.z; a0.w += b0.w;
    a1.x += b1.x; a1.y += b1.y; a1.z += b1.z; a1.w += b1.w;

    float di = dinv[n];
    float4 bv0 = ((const float4*)bias)[2 * hl];
    float4 bv1 = ((const float4*)bias)[2 * hl + 1];
    float o0 = di * a0.x + bv0.x, o1 = di * a0.y + bv0.y;
    float o2 = di * a0.z + bv0.z, o3 = di * a0.w + bv0.w;
    float o4 = di * a1.x + bv1.x, o5 = di * a1.y + bv1.y;
    float o6 = di * a1.z + bv1.z, o7 = di * a1.w + bv1.w;
    if (do_relu) {
        o0 = fmaxf(o0, 0.f); o1 = fmaxf(o1, 0.f); o2 = fmaxf(o2, 0.f); o3 = fmaxf(o3, 0.f);
        o4 = fmaxf(o4, 0.f); o5 = fmaxf(o5, 0.f); o6 = fmaxf(o6, 0.f); o7 = fmaxf(o7, 0.f);
    }
    uint4 o;
    o.x = pack2(o0, o1);
    o.y = pack2(o2, o3);
    o.z = pack2(o4, o5);
    o.w = pack2(o6, o7);
    ((uint4*)Z)[(size_t)n * 16 + hl] = o;
}

// R14 decode: pairs bucket-sorted by A. 2 blocks per bucket; each block stages the
// bucket's 64 A-rows (16KB, padded stride 136 shorts) into LDS, then 16-lane groups
// process pairs (4 in flight): A-row from LDS + B-row random gather from global.
// Random gather traffic halves vs per-pair gathers of both rows. Dot order preserved.
__global__ __launch_bounds__(256) void decode_bucket_kernel(const unsigned short* __restrict__ Zp,
                                                            const unsigned int* __restrict__ stageP,
                                                            const int* __restrict__ pair_base,
                                                            const int* __restrict__ pb,
                                                            float* __restrict__ out,
                                                            int N) {
    __shared__ __align__(16) short AL[64 * 136];
    const int tid = threadIdx.x;
    const int blk = blockIdx.x >> 1;
    const int half = blockIdx.x & 1;
    const uint4* Z4 = (const uint4*)Zp;

    // stage A rows (coalesced; rows beyond N clamp to N-1, never referenced by pairs)
#pragma unroll
    for (int i = 0; i < 4; ++i) {
        int idx = tid + i * 256;        // [0,1024)
        int row = idx >> 4, hl = idx & 15;
        int gr = min(blk * 64 + row, N - 1);
        *(uint4*)&AL[row * 136 + hl * 8] = Z4[(size_t)gr * 16 + hl];
    }
    __syncthreads();

    int base = pair_base[blk], basen = pair_base[blk + 1];
    int gp = half * 16 + (tid >> 4);    // group id in [0,32)
    int hl = tid & 15;

    for (int k = base + gp; k < basen; k += 128) {
        int i1 = k + 32, i2 = k + 64, i3 = k + 96;
        bool h1 = i1 < basen, h2 = i2 < basen, h3 = i3 < basen;
        unsigned r0 = stageP[k];
        unsigned r1 = h1 ? stageP[i1] : r0;
        unsigned r2 = h2 ? stageP[i2] : r0;
        unsigned r3 = h3 ? stageP[i3] : r0;
        int p0 = (int)(r0 >> 6), p1 = (int)(r1 >> 6);
        int p2 = (int)(r2 >> 6), p3 = (int)(r3 >> 6);
        int B0 = pb[p0], B1 = pb[p1], B2 = pb[p2], B3 = pb[p3];
        uint4 ub0 = Z4[(size_t)B0 * 16 + hl];
        uint4 ub1 = Z4[(size_t)B1 * 16 + hl];
        uint4 ub2 = Z4[(size_t)B2 * 16 + hl];
        uint4 ub3 = Z4[(size_t)B3 * 16 + hl];
        uint4 ua0 = *(const uint4*)&AL[(int)(r0 & 63u) * 136 + hl * 8];
        uint4 ua1 = *(const uint4*)&AL[(int)(r1 & 63u) * 136 + hl * 8];
        uint4 ua2 = *(const uint4*)&AL[(int)(r2 & 63u) * 136 + hl * 8];
        uint4 ua3 = *(const uint4*)&AL[(int)(r3 & 63u) * 136 + hl * 8];

        float4 xa, xb, ya, yb;
        xa = cvt4(ua0.x, ua0.y); xb = cvt4(ub0.x, ub0.y);
        ya = cvt4(ua0.z, ua0.w); yb = cvt4(ub0.z, ub0.w);
        float v0 = xa.x * xb.x + xa.y * xb.y + xa.z * xb.z + xa.w * xb.w
                 + ya.x * yb.x + ya.y * yb.y + ya.z * yb.z + ya.w * yb.w;
        xa = cvt4(ua1.x, ua1.y); xb = cvt4(ub1.x, ub1.y);
        ya = cvt4(ua1.z, ua1.w); yb = cvt4(ub1.z, ub1.w);
        float v1 = xa.x * xb.x + xa.y * xb.y + xa.z * xb.z + xa.w * xb.w
                 + ya.x * yb.x + ya.y * yb.y + ya.z * yb.z + ya.w * yb.w;
        xa = cvt4(ua2.x, ua2.y); xb = cvt4(ub2.x, ub2.y);
        ya = cvt4(ua2.z, ua2.w); yb = cvt4(ub2.z, ub2.w);
        float v2 = xa.x * xb.x + xa.y * xb.y + xa.z * xb.z + xa.w * xb.w
                 + ya.x * yb.x + ya.y * yb.y + ya.z * yb.z + ya.w * yb.w;
        xa = cvt4(ua3.x, ua3.y); xb = cvt4(ub3.x, ub3.y);
        ya = cvt4(ua3.z, ua3.w); yb = cvt4(ub3.z, ub3.w);
        float v3 = xa.x * xb.x + xa.y * xb.y + xa.z * xb.z + xa.w * xb.w
                 + ya.x * yb.x + ya.y * yb.y + ya.z * yb.z + ya.w * yb.w;
#pragma unroll
        for (int off = 8; off > 0; off >>= 1) {
            v0 += __shfl_down(v0, off, 16);
            v1 += __shfl_down(v1, off, 16);
            v2 += __shfl_down(v2, off, 16);
            v3 += __shfl_down(v3, off, 16);
        }
        if (hl == 0) {
            out[p0] = v0;
            if (h1) out[p1] = v1;
            if (h2) out[p2] = v2;
            if (h3) out[p3] = v3;
        }
    }
}

extern "C" void kernel_launch(void* const* d_in, const int* in_sizes, int n_in,
                              void* d_out, int out_size, void* d_ws, size_t ws_size,
                              hipStream_t stream) {
    const int*   edge_index = (const int*)d_in[0];
    const int*   edge_pairs = (const int*)d_in[1];
    const float* emb        = (const float*)d_in[2];
    const float* W1         = (const float*)d_in[3];
    const float* b1         = (const float*)d_in[4];
    const float* W2         = (const float*)d_in[5];
    const float* b2         = (const float*)d_in[6];
    float* out = (float*)d_out;

    int E = in_sizes[0] / 2;
    int P = in_sizes[1] / 2;
    int N = in_sizes[2] / 128;
    int NB = (N + 63) / 64;    // buckets == gemm tiles (782 for N=50000; must be <= 1024)

    const int* src = edge_index;
    const int* dst = edge_index + E;
    const int* pa  = edge_pairs;
    const int* pb  = edge_pairs + P;

    char* ws = (char*)d_ws;
    size_t off = 0;
    auto alloc = [&](size_t bytes) -> void* {
        void* p = ws + off;
        off = (off + bytes + 255) & ~(size_t)255;
        return p;
    };
    unsigned short* bufA = (unsigned short*)alloc((size_t)N * 128 * 2); // h1' then h2'
    unsigned short* bufB = (unsigned short*)alloc((size_t)N * 128 * 2); // z1 then z2
    int*   srcs_sorted  = (int*)alloc((size_t)E * sizeof(int));
    unsigned int* stage = (unsigned int*)alloc((size_t)E * sizeof(unsigned int));
    int*   row_ptr      = (int*)alloc((size_t)(N + 1) * sizeof(int));
    float* dinv         = (float*)alloc((size_t)N * sizeof(float));
    int*   bhist        = (int*)alloc((size_t)STAGE_G * NB * sizeof(int));
    int*   T            = (int*)alloc((size_t)NB * sizeof(int));
    int*   bucket_base  = (int*)alloc((size_t)(NB + 1) * sizeof(int));
    // R14 additions
    int*   phist        = (int*)alloc((size_t)STAGE_G * NB * sizeof(int));
    int*   T2           = (int*)alloc((size_t)NB * sizeof(int));
    int*   pair_base    = (int*)alloc((size_t)(NB + 1) * sizeof(int));
    unsigned int* stageP = (unsigned int*)alloc((size_t)P * sizeof(unsigned int));
    short* wb1          = (short*)alloc((size_t)16384 * sizeof(short));
    short* wb2          = (short*)alloc((size_t)16384 * sizeof(short));

    // CSR build front half (3 dispatches); hist also prepacks W1/W2 + pair histogram
    block_hist_kernel<<<STAGE_G, 256, 0, stream>>>(dst, pa, bhist, phist, W1, W2,
                                                   wb1, wb2, E, P, NB);
    s1_scan_blocks<<<NB, 128, 0, stream>>>(bhist, phist, T, T2, NB);
    stage_kernel<<<STAGE_G, 256, 0, stream>>>(src, dst, pa, bhist, phist, T, T2,
                                              bucket_base, pair_base, stage, stageP,
                                              E, P, NB);

    // FUSED scatter + gemm1: CSR finalize + h1' = dinv*(emb@W1) -> bufA
    scatter_gemm_kernel<<<NB, 256, 0, stream>>>(stage, bucket_base, row_ptr, dinv,
                                                srcs_sorted, emb, wb1, (uint2*)bufA, N);

    // agg1: z1 = relu(dinv*(h1'+sum)+b1) -> bufB
    agg_kernel<<<(N + 15) / 16, 256, 0, stream>>>(bufA, row_ptr, srcs_sorted, dinv, b1,
                                                  bufB, N, 1);

    // gemm2: h2' = dinv*(z1@W2) -> bufA
    gemm_mfma_kernel<<<NB, 256, 0, stream>>>(bufB, wb2, dinv, (uint2*)bufA, N);

    // agg2: z2 = dinv*(h2'+sum)+b2 -> bufB
    agg_kernel<<<(N + 15) / 16, 256, 0, stream>>>(bufA, row_ptr, srcs_sorted, dinv, b2,
                                                  bufB, N, 0);

    // Decode: bucket-sorted pairs, A-rows from LDS, B-rows gathered (2 blocks/bucket)
    decode_bucket_kernel<<<NB * 2, 256, 0, stream>>>(bufB, stageP, pair_base, pb, out, N);
}

// Round 3
// 228.743 us; speedup vs baseline: 1.3659x; 1.1113x over previous
//
#include <hip/hip_runtime.h>

// GCN link predictor. fp32 math, bf16 intermediates + bf16 MFMA GEMM.
// Pipeline: memset(cnts) -> stage1[hist+reserve+scatter edges&pairs + Wprepack] ->
//           FUSED[scatter+gemm1] -> agg1 -> gemm2 -> agg2 -> decode-bucket.  (7 dispatches)
// norm factorization: h'[i] = dinv[i]*(x@W)[i];  z[i] = dinv[i]*(h'[i] + sum_{src->i} h'[src]) + b.
// R5: MFMA GEMM. R6 FAILED: hot per-row global atomics. R7: deterministic bucket CSR. R8: 248us.
// R9 FAILED: grid.sync. R10: quarter-wave gathers (neutral; random-line floor ~4.5TB/s).
// R11 FAILED: agg1+gemm2 fusion cut gather parallelism. R12: fuse scatter+gemm1 (244.8us).
// R13 FAILED (312us): column-pass L2 blocking -- per-XCD reuse E/(8N)=2, can't beat LLC floor.
// R14 (254us, ~neutral): decode A-bucket + LDS staging halved B-gather lines but refunded the
// win via random 4B pb reads + random 4B out writes (a 4B random touch costs a full line).
// R15: (a) pair record = uint2{(B<<6)|(A&63), pidx} -- pb read moves to staging (coalesced),
// decode loses 0.4M random lines. (b) fixed-capacity strided buckets (ECAP/PCAP) with
// LDS-hist + global range-reserve: CSR front 3 dispatches -> 1 (+tiny memset); exact prefix
// scans deleted. rpd[n] packs (start<<7)|deg into strided srcs. agg1/agg2 at floor, untouched.

typedef __attribute__((ext_vector_type(8))) short short8;   // 8 bf16 (A/B frag)
typedef __attribute__((ext_vector_type(4))) float floatx4;  // C/D frag

#define STAGE_G 128   // staging blocks
#define ECAP 2048     // per-bucket edge capacity   (lambda~1024; overflow ~impossible, guarded)
#define PCAP 1024     // per-bucket pair capacity   (lambda~511)

__device__ __forceinline__ unsigned short f2bf(float f) {
    union { float f; unsigned int u; } v; v.f = f;
    unsigned int u = v.u;
    u += 0x7fffu + ((u >> 16) & 1u);   // round-to-nearest-even
    return (unsigned short)(u >> 16);
}

__device__ __forceinline__ unsigned int pack2(float a, float b) {
    return (unsigned int)f2bf(a) | ((unsigned int)f2bf(b) << 16);
}

__device__ __forceinline__ float4 cvt4(unsigned int lo, unsigned int hi) {
    float4 f;
    f.x = __uint_as_float(lo << 16);
    f.y = __uint_as_float(lo & 0xffff0000u);
    f.z = __uint_as_float(hi << 16);
    f.w = __uint_as_float(hi & 0xffff0000u);
    return f;
}

// --- single-pass bucket staging (edges + pairs) + W prepack ---
// Per block: LDS histogram of its chunk -> one global atomicAdd range-reserve per touched
// bucket -> LDS-cursor scatter into fixed-stride bucket regions. No exact prefix needed.
__global__ __launch_bounds__(256) void stage1_kernel(const int* __restrict__ src,
                                                     const int* __restrict__ dst,
                                                     const int* __restrict__ pa,
                                                     const int* __restrict__ pb,
                                                     int* __restrict__ ecnt,
                                                     int* __restrict__ pcnt,
                                                     unsigned int* __restrict__ stageE,
                                                     uint2* __restrict__ stageP,
                                                     const float* __restrict__ W1,
                                                     const float* __restrict__ W2,
                                                     short* __restrict__ wb1,
                                                     short* __restrict__ wb2,
                                                     int E, int P, int NB) {
    __shared__ int bh[1024];
    __shared__ int bh2[1024];
    int t = threadIdx.x, g = blockIdx.x;

    // one-time W prepack into MFMA B layout: WB[((nt*4+kt)*64+ln)*8+j]
    if (g < 32) {
        const float4* W4 = (const float4*)((g < 16) ? W1 : W2);
        short* wb = (g < 16) ? wb1 : wb2;
        int f = ((g & 15) * 256) + t;          // f in [0,4096)
        int k = f >> 5;
        int c4 = f & 31;
        float4 wv = W4[f];
        int kt = k >> 5, q = (k >> 3) & 3, j = k & 7;
        float e[4] = {wv.x, wv.y, wv.z, wv.w};
#pragma unroll
        for (int m = 0; m < 4; ++m) {
            int c = c4 * 4 + m;
            int nt = c >> 4;
            int ln = q * 16 + (c & 15);
            wb[((nt * 4 + kt) * 64 + ln) * 8 + j] = (short)f2bf(e[m]);
        }
    }

    for (int b = t; b < NB; b += 256) { bh[b] = 0; bh2[b] = 0; }
    __syncthreads();

    int chunk = (E + gridDim.x - 1) / gridDim.x;
    int lo = g * chunk, hi = min(lo + chunk, E);
    int chunkP = (P + gridDim.x - 1) / gridDim.x;
    int loP = g * chunkP, hiP = min(loP + chunkP, P);

    // pass 1: count
    for (int i = lo + t; i < hi; i += 256) atomicAdd(&bh[dst[i] >> 6], 1);
    for (int i = loP + t; i < hiP; i += 256) atomicAdd(&bh2[pa[i] >> 6], 1);
    __syncthreads();

    // reserve: bh[b] becomes this block's base (local index within bucket b)
    for (int b = t; b < NB; b += 256) {
        int c = bh[b];
        if (c) bh[b] = atomicAdd(&ecnt[b], c);
        int c2 = bh2[b];
        if (c2) bh2[b] = atomicAdd(&pcnt[b], c2);
    }
    __syncthreads();

    // pass 2: scatter into strided bucket regions
    for (int i = lo + t; i < hi; i += 256) {
        int d = dst[i];
        int b = d >> 6;
        int pos = atomicAdd(&bh[b], 1);
        if (pos < ECAP)
            stageE[(b << 11) + pos] = ((unsigned int)src[i] << 6) | (unsigned int)(d & 63);
    }
    for (int i = loP + t; i < hiP; i += 256) {
        int A = pa[i];
        int b = A >> 6;
        int pos = atomicAdd(&bh2[b], 1);
        if (pos < PCAP) {
            uint2 r;
            r.x = ((unsigned int)pb[i] << 6) | (unsigned int)(A & 63);  // B < 2^26
            r.y = (unsigned int)i;
            stageP[(b << 10) + pos] = r;
        }
    }
}

// --- FUSED scatter + layer-1 GEMM. One block per bucket b == one 64-row gemm tile.
__global__ __launch_bounds__(256) void scatter_gemm_kernel(const unsigned int* __restrict__ stageE,
                                                           const int* __restrict__ ecnt,
                                                           unsigned int* __restrict__ rpd,
                                                           float* __restrict__ dinv,
                                                           int* __restrict__ srcs_sorted,
                                                           const float* __restrict__ Xv,
                                                           const short* __restrict__ wbpre,
                                                           uint2* __restrict__ H, int N) {
    __shared__ __align__(16) char smem[50176];
    __shared__ int cnt[64];
    __shared__ int lcur[64];
    __shared__ float sdinv[64];
    short* WB = (short*)smem;            // [nt][kt][lane][j]
    short* XL = (short*)(smem + 32768);  // [row][k], row stride 136 shorts
    float* Cst = (float*)smem;           // epilogue overlay: [row][col], stride 132 floats

    const int tid = threadIdx.x;
    const int blk = blockIdx.x;

    // ---- Phase 1: bucket CSR finalize ----
    {
        int t = tid;
        int lo = blk << 6;
        int base = blk << 11;            // blk*ECAP
        int cntE = ecnt[blk];
        if (t < 64) cnt[t] = 0;
        __syncthreads();
        for (int i = t; i < cntE; i += 256) atomicAdd(&cnt[stageE[base + i] & 63u], 1);
        __syncthreads();
        if (t < 64) {
            int v = cnt[t];
            int inc = v;
#pragma unroll
            for (int off = 1; off < 64; off <<= 1) {
                int x = __shfl_up(inc, off, 64);
                if (t >= off) inc += x;
            }
            int exc = inc - v;
            int node = lo + t;
            int start = base + exc;      // index into strided srcs_sorted
            float di = rsqrtf((float)(v + 1));   // +1 self-loop
            if (node < N) {
                rpd[node] = ((unsigned int)start << 7) | (unsigned int)v;  // deg < 128
                dinv[node] = di;
                sdinv[t] = di;
            } else {
                sdinv[t] = 0.f;
            }
            lcur[t] = start;
        }
        __syncthreads();
        for (int i = t; i < cntE; i += 256) {
            unsigned int rec = stageE[base + i];
            int pos = atomicAdd(&lcur[rec & 63u], 1);
            srcs_sorted[pos] = (int)(rec >> 6);
        }
    }
    __syncthreads();

    // ---- Phase 2: gemm1 (fp32 X @ W -> bf16 H, dinv from LDS) ----
    {
        const uint4* Wp = (const uint4*)wbpre;
        uint4* WB4 = (uint4*)WB;
#pragma unroll
        for (int i = 0; i < 8; ++i) {
            int idx = tid + i * 256;   // [0,2048)
            WB4[idx] = Wp[idx];
        }
    }
    {
#pragma unroll
        for (int i = 0; i < 8; ++i) {
            int f = tid + i * 256;
            int row = f >> 5;
            int c4 = f & 31;
            int gr = min(blk * 64 + row, N - 1);
            float4 xv = ((const float4*)Xv)[(size_t)gr * 32 + c4];
            uint2 u;
            u.x = pack2(xv.x, xv.y);
            u.y = pack2(xv.z, xv.w);
            *(uint2*)&XL[row * 136 + c4 * 4] = u;
        }
    }
    __syncthreads();

    const int w = tid >> 6;
    const int lane = tid & 63;
    const int arow = w * 16 + (lane & 15);
    const int koff = (lane >> 4) * 8;
    short8 a[4];
#pragma unroll
    for (int kt = 0; kt < 4; ++kt)
        a[kt] = *(const short8*)&XL[arow * 136 + kt * 32 + koff];

    floatx4 acc[8];
#pragma unroll
    for (int nt = 0; nt < 8; ++nt) acc[nt] = (floatx4){0.f, 0.f, 0.f, 0.f};

#pragma unroll
    for (int kt = 0; kt < 4; ++kt) {
#pragma unroll
        for (int nt = 0; nt < 8; ++nt) {
            short8 b = *(const short8*)&WB[((nt * 4 + kt) * 64 + lane) * 8];
            acc[nt] = __builtin_amdgcn_mfma_f32_16x16x32_bf16(a[kt], b, acc[nt], 0, 0, 0);
        }
    }
    __syncthreads();

    {
        int q = lane >> 4, cn = lane & 15;
#pragma unroll
        for (int nt = 0; nt < 8; ++nt)
#pragma unroll
            for (int r = 0; r < 4; ++r)
                Cst[(w * 16 + q * 4 + r) * 132 + nt * 16 + cn] = acc[nt][r];
    }
    __syncthreads();
    {
#pragma unroll
        for (int i = 0; i < 8; ++i) {
            int f = tid + i * 256;
            int row = f >> 5;
            int c4 = f & 31;
            int gr = blk * 64 + row;
            if (gr < N) {
                float4 v = *(float4*)&Cst[row * 132 + c4 * 4];
                float di = sdinv[row];
                uint2 o;
                o.x = pack2(v.x * di, v.y * di);
                o.y = pack2(v.z * di, v.w * di);
                H[(size_t)gr * 32 + c4] = o;
            }
        }
    }
}

// --- standalone MFMA GEMM (layer 2, bf16 input, prepacked W) ---
__global__ __launch_bounds__(256) void gemm_mfma_kernel(const unsigned short* __restrict__ Xv,
                                                        const short* __restrict__ wbpre,
                                                        const float* __restrict__ dinv,
                                                        uint2* __restrict__ H, int N) {
    __shared__ __align__(16) char smem[50176];
    short* WB = (short*)smem;
    short* XL = (short*)(smem + 32768);
    float* Cst = (float*)smem;

    const int tid = threadIdx.x;
    const int w = tid >> 6;
    const int lane = tid & 63;
    const int blk = blockIdx.x;

    {
        const uint4* Wp = (const uint4*)wbpre;
        uint4* WB4 = (uint4*)WB;
#pragma unroll
        for (int i = 0; i < 8; ++i) {
            int idx = tid + i * 256;
            WB4[idx] = Wp[idx];
        }
    }
    {
#pragma unroll
        for (int i = 0; i < 8; ++i) {
            int f = tid + i * 256;
            int row = f >> 5;
            int c4 = f & 31;
            int gr = min(blk * 64 + row, N - 1);
            uint2 u = ((const uint2*)Xv)[(size_t)gr * 32 + c4];
            *(uint2*)&XL[row * 136 + c4 * 4] = u;
        }
    }
    __syncthreads();

    const int arow = w * 16 + (lane & 15);
    const int koff = (lane >> 4) * 8;
    short8 a[4];
#pragma unroll
    for (int kt = 0; kt < 4; ++kt)
        a[kt] = *(const short8*)&XL[arow * 136 + kt * 32 + koff];

    floatx4 acc[8];
#pragma unroll
    for (int nt = 0; nt < 8; ++nt) acc[nt] = (floatx4){0.f, 0.f, 0.f, 0.f};

#pragma unroll
    for (int kt = 0; kt < 4; ++kt) {
#pragma unroll
        for (int nt = 0; nt < 8; ++nt) {
            short8 b = *(const short8*)&WB[((nt * 4 + kt) * 64 + lane) * 8];
            acc[nt] = __builtin_amdgcn_mfma_f32_16x16x32_bf16(a[kt], b, acc[nt], 0, 0, 0);
        }
    }
    __syncthreads();

    {
        int q = lane >> 4, cn = lane & 15;
#pragma unroll
        for (int nt = 0; nt < 8; ++nt)
#pragma unroll
            for (int r = 0; r < 4; ++r)
                Cst[(w * 16 + q * 4 + r) * 132 + nt * 16 + cn] = acc[nt][r];
    }
    __syncthreads();
    {
#pragma unroll
        for (int i = 0; i < 8; ++i) {
            int f = tid + i * 256;
            int row = f >> 5;
            int c4 = f & 31;
            int gr = blk * 64 + row;
            if (gr < N) {
                float4 v = *(float4*)&Cst[row * 132 + c4 * 4];
                float di = dinv[gr];
                uint2 o;
                o.x = pack2(v.x * di, v.y * di);
                o.y = pack2(v.z * di, v.w * di);
                H[(size_t)gr * 32 + c4] = o;
            }
        }
    }
}

// Quarter-wave (16 lanes) per node; lane holds 8 cols as uint4. fp32 accumulate.
// rpd[n] = (start<<7)|deg into strided srcs (deg < 128, Poisson-16: safe).
__global__ __launch_bounds__(256) void agg_kernel(const unsigned short* __restrict__ Hp,
                                                  const unsigned int* __restrict__ rpd,
                                                  const int* __restrict__ srcs,
                                                  const float* __restrict__ dinv,
                                                  const float* __restrict__ bias,
                                                  unsigned short* __restrict__ Z,
                                                  int N, int do_relu) {
    int gw = (int)((blockIdx.x * blockDim.x + threadIdx.x) >> 6);
    int lane = threadIdx.x & 63;
    int q = lane >> 4;
    int hl = lane & 15;
    int n = gw * 4 + q;
    if (n >= N) return;

    const uint4* H4 = (const uint4*)Hp;
    uint4 us = H4[(size_t)n * 16 + hl];
    float4 a0 = cvt4(us.x, us.y);
    float4 a1 = cvt4(us.z, us.w);
    float4 b0 = make_float4(0.f, 0.f, 0.f, 0.f);
    float4 b1 = make_float4(0.f, 0.f, 0.f, 0.f);

    unsigned int rp = rpd[n];
    int j = (int)(rp >> 7), end = j + (int)(rp & 127u);
    for (; j + 7 < end; j += 8) {
        uint4 u0 = H4[(size_t)srcs[j + 0] * 16 + hl];
        uint4 u1 = H4[(size_t)srcs[j + 1] * 16 + hl];
        uint4 u2 = H4[(size_t)srcs[j + 2] * 16 + hl];
        uint4 u3 = H4[(size_t)srcs[j + 3] * 16 + hl];
        uint4 u4 = H4[(size_t)srcs[j + 4] * 16 + hl];
        uint4 u5 = H4[(size_t)srcs[j + 5] * 16 + hl];
        uint4 u6 = H4[(size_t)srcs[j + 6] * 16 + hl];
        uint4 u7 = H4[(size_t)srcs[j + 7] * 16 + hl];
        float4 t;
        t = cvt4(u0.x, u0.y); a0.x += t.x; a0.y += t.y; a0.z += t.z; a0.w += t.w;
        t = cvt4(u0.z, u0.w); a1.x += t.x; a1.y += t.y; a1.z += t.z; a1.w += t.w;
        t = cvt4(u1.x, u1.y); b0.x += t.x; b0.y += t.y; b0.z += t.z; b0.w += t.w;
        t = cvt4(u1.z, u1.w); b1.x += t.x; b1.y += t.y; b1.z += t.z; b1.w += t.w;
        t = cvt4(u2.x, u2.y); a0.x += t.x; a0.y += t.y; a0.z += t.z; a0.w += t.w;
        t = cvt4(u2.z, u2.w); a1.x += t.x; a1.y += t.y; a1.z += t.z; a1.w += t.w;
        t = cvt4(u3.x, u3.y); b0.x += t.x; b0.y += t.y; b0.z += t.z; b0.w += t.w;
        t = cvt4(u3.z, u3.w); b1.x += t.x; b1.y += t.y; b1.z += t.z; b1.w += t.w;
        t = cvt4(u4.x, u4.y); a0.x += t.x; a0.y += t.y; a0.z += t.z; a0.w += t.w;
        t = cvt4(u4.z, u4.w); a1.x += t.x; a1.y += t.y; a1.z += t.z; a1.w += t.w;
        t = cvt4(u5.x, u5.y); b0.x += t.x; b0.y += t.y; b0.z += t.z; b0.w += t.w;
        t = cvt4(u5.z, u5.w); b1.x += t.x; b1.y += t.y; b1.z += t.z; b1.w += t.w;
        t = cvt4(u6.x, u6.y); a0.x += t.x; a0.y += t.y; a0.z += t.z; a0.w += t.w;
        t = cvt4(u6.z, u6.w); a1.x += t.x; a1.y += t.y; a1.z += t.z; a1.w += t.w;
        t = cvt4(u7.x, u7.y); b0.x += t.x; b0.y += t.y; b0.z += t.z; b0.w += t.w;
        t = cvt4(u7.z, u7.w); b1.x += t.x; b1.y += t.y; b1.z += t.z; b1.w += t.w;
    }
    for (; j + 3 < end; j += 4) {
        uint4 u0 = H4[(size_t)srcs[j + 0] * 16 + hl];
        uint4 u1 = H4[(size_t)srcs[j + 1] * 16 + hl];
        uint4 u2 = H4[(size_t)srcs[j + 2] * 16 + hl];
        uint4 u3 = H4[(size_t)srcs[j + 3] * 16 + hl];
        float4 t;
        t = cvt4(u0.x, u0.y); a0.x += t.x; a0.y += t.y; a0.z += t.z; a0.w += t.w;
        t = cvt4(u0.z, u0.w); a1.x += t.x; a1.y += t.y; a1.z += t.z; a1.w += t.w;
        t = cvt4(u1.x, u1.y); b0.x += t.x; b0.y += t.y; b0.z += t.z; b0.w += t.w;
        t = cvt4(u1.z, u1.w); b1.x += t.x; b1.y += t.y; b1.z += t.z; b1.w += t.w;
        t = cvt4(u2.x, u2.y); a0.x += t.x; a0.y += t.y; a0.z += t.z; a0.w += t.w;
        t = cvt4(u2.z, u2.w); a1.x += t.x; a1.y += t.y; a1.z += t.z; a1.w += t.w;
        t = cvt4(u3.x, u3.y); b0.x += t.x; b0.y += t.y; b0.z += t.z; b0.w += t.w;
        t = cvt4(u3.z, u3.w); b1.x += t.x; b1.y += t.y; b1.z += t.z; b1.w += t.w;
    }
    for (; j < end; ++j) {
        uint4 u = H4[(size_t)srcs[j] * 16 + hl];
        float4 t;
        t = cvt4(u.x, u.y); a0.x += t.x; a0.y += t.y; a0.z += t.z; a0.w += t.w;
        t = cvt4(u.z, u.w); a1.x += t.x; a1.y += t.y; a1.z += t.z; a1.w += t.w;
    }
    a0.x += b0.x; a0.y += b0.y; a0.z += b0.z; a0.w += b0.w;
    a1.x += b1.x; a1.y += b1.y; a1.z += b1.z; a1.w += b1.w;

    float di = dinv[n];
    float4 bv0 = ((const float4*)bias)[2 * hl];
    float4 bv1 = ((const float4*)bias)[2 * hl + 1];
    float o0 = di * a0.x + bv0.x, o1 = di * a0.y + bv0.y;
    float o2 = di * a0.z + bv0.z, o3 = di * a0.w + bv0.w;
    float o4 = di * a1.x + bv1.x, o5 = di * a1.y + bv1.y;
    float o6 = di * a1.z + bv1.z, o7 = di * a1.w + bv1.w;
    if (do_relu) {
        o0 = fmaxf(o0, 0.f); o1 = fmaxf(o1, 0.f); o2 = fmaxf(o2, 0.f); o3 = fmaxf(o3, 0.f);
        o4 = fmaxf(o4, 0.f); o5 = fmaxf(o5, 0.f); o6 = fmaxf(o6, 0.f); o7 = fmaxf(o7, 0.f);
    }
    uint4 o;
    o.x = pack2(o0, o1);
    o.y = pack2(o2, o3);
    o.z = pack2(o4, o5);
    o.w = pack2(o6, o7);
    ((uint4*)Z)[(size_t)n * 16 + hl] = o;
}

// Decode: pairs bucket-sorted by A, B index embedded in the record (no random pb read).
// 2 blocks per bucket; block stages the bucket's 64 A-rows (16KB) in LDS; 16-lane groups
// process 4 pairs in flight: A from LDS + B random row-gather. out[pidx] random 4B write.
__global__ __launch_bounds__(256) void decode_bucket_kernel(const unsigned short* __restrict__ Zp,
                                                            const uint2* __restrict__ stageP,
                                                            const int* __restrict__ pcnt,
                                                            float* __restrict__ out,
                                                            int N) {
    __shared__ __align__(16) short AL[64 * 136];
    const int tid = threadIdx.x;
    const int blk = blockIdx.x >> 1;
    const int half = blockIdx.x & 1;
    const uint2* SP = stageP + ((size_t)blk << 10);   // blk*PCAP
    const uint4* Z4 = (const uint4*)Zp;

    // stage A rows (coalesced; rows beyond N clamp to N-1, never referenced by pairs)
#pragma unroll
    for (int i = 0; i < 4; ++i) {
        int idx = tid + i * 256;        // [0,1024)
        int row = idx >> 4, hl = idx & 15;
        int gr = min(blk * 64 + row, N - 1);
        *(uint4*)&AL[row * 136 + hl * 8] = Z4[(size_t)gr * 16 + hl];
    }
    __syncthreads();

    int cntP = pcnt[blk];
    int gp = half * 16 + (tid >> 4);    // group id in [0,32)
    int hl = tid & 15;

    for (int k = gp; k < cntP; k += 128) {
        int i1 = k + 32, i2 = k + 64, i3 = k + 96;
        bool h1 = i1 < cntP, h2 = i2 < cntP, h3 = i3 < cntP;
        uint2 r0 = SP[k];
        uint2 r1 = h1 ? SP[i1] : r0;
        uint2 r2 = h2 ? SP[i2] : r0;
        uint2 r3 = h3 ? SP[i3] : r0;
        int B0 = (int)(r0.x >> 6), B1 = (int)(r1.x >> 6);
        int B2 = (int)(r2.x >> 6), B3 = (int)(r3.x >> 6);
        uint4 ub0 = Z4[(size_t)B0 * 16 + hl];
        uint4 ub1 = Z4[(size_t)B1 * 16 + hl];
        uint4 ub2 = Z4[(size_t)B2 * 16 + hl];
        uint4 ub3 = Z4[(size_t)B3 * 16 + hl];
        uint4 ua0 = *(const uint4*)&AL[(int)(r0.x & 63u) * 136 + hl * 8];
        uint4 ua1 = *(const uint4*)&AL[(int)(r1.x & 63u) * 136 + hl * 8];
        uint4 ua2 = *(const uint4*)&AL[(int)(r2.x & 63u) * 136 + hl * 8];
        uint4 ua3 = *(const uint4*)&AL[(int)(r3.x & 63u) * 136 + hl * 8];

        float4 xa, xb, ya, yb;
        xa = cvt4(ua0.x, ua0.y); xb = cvt4(ub0.x, ub0.y);
        ya = cvt4(ua0.z, ua0.w); yb = cvt4(ub0.z, ub0.w);
        float v0 = xa.x * xb.x + xa.y * xb.y + xa.z * xb.z + xa.w * xb.w
                 + ya.x * yb.x + ya.y * yb.y + ya.z * yb.z + ya.w * yb.w;
        xa = cvt4(ua1.x, ua1.y); xb = cvt4(ub1.x, ub1.y);
        ya = cvt4(ua1.z, ua1.w); yb = cvt4(ub1.z, ub1.w);
        float v1 = xa.x * xb.x + xa.y * xb.y + xa.z * xb.z + xa.w * xb.w
                 + ya.x * yb.x + ya.y * yb.y + ya.z * yb.z + ya.w * yb.w;
        xa = cvt4(ua2.x, ua2.y); xb = cvt4(ub2.x, ub2.y);
        ya = cvt4(ua2.z, ua2.w); yb = cvt4(ub2.z, ub2.w);
        float v2 = xa.x * xb.x + xa.y * xb.y + xa.z * xb.z + xa.w * xb.w
                 + ya.x * yb.x + ya.y * yb.y + ya.z * yb.z + ya.w * yb.w;
        xa = cvt4(ua3.x, ua3.y); xb = cvt4(ub3.x, ub3.y);
        ya = cvt4(ua3.z, ua3.w); yb = cvt4(ub3.z, ub3.w);
        float v3 = xa.x * xb.x + xa.y * xb.y + xa.z * xb.z + xa.w * xb.w
                 + ya.x * yb.x + ya.y * yb.y + ya.z * yb.z + ya.w * yb.w;
#pragma unroll
        for (int off = 8; off > 0; off >>= 1) {
            v0 += __shfl_down(v0, off, 16);
            v1 += __shfl_down(v1, off, 16);
            v2 += __shfl_down(v2, off, 16);
            v3 += __shfl_down(v3, off, 16);
        }
        if (hl == 0) {
            out[r0.y] = v0;
            if (h1) out[r1.y] = v1;
            if (h2) out[r2.y] = v2;
            if (h3) out[r3.y] = v3;
        }
    }
}

extern "C" void kernel_launch(void* const* d_in, const int* in_sizes, int n_in,
                              void* d_out, int out_size, void* d_ws, size_t ws_size,
                              hipStream_t stream) {
    const int*   edge_index = (const int*)d_in[0];
    const int*   edge_pairs = (const int*)d_in[1];
    const float* emb        = (const float*)d_in[2];
    const float* W1         = (const float*)d_in[3];
    const float* b1         = (const float*)d_in[4];
    const float* W2         = (const float*)d_in[5];
    const float* b2         = (const float*)d_in[6];
    float* out = (float*)d_out;

    int E = in_sizes[0] / 2;
    int P = in_sizes[1] / 2;
    int N = in_sizes[2] / 128;
    int NB = (N + 63) / 64;    // buckets == gemm tiles (782 for N=50000; must be <= 1024)

    const int* src = edge_index;
    const int* dst = edge_index + E;
    const int* pa  = edge_pairs;
    const int* pb  = edge_pairs + P;

    char* ws = (char*)d_ws;
    size_t off = 0;
    auto alloc = [&](size_t bytes) -> void* {
        void* p = ws + off;
        off = (off + bytes + 255) & ~(size_t)255;
        return p;
    };
    unsigned short* bufA = (unsigned short*)alloc((size_t)N * 128 * 2); // h1' then h2'
    unsigned short* bufB = (unsigned short*)alloc((size_t)N * 128 * 2); // z1 then z2
    int*   srcs_sorted  = (int*)alloc((size_t)NB * ECAP * sizeof(int));
    unsigned int* stageE = (unsigned int*)alloc((size_t)NB * ECAP * sizeof(unsigned int));
    uint2* stageP       = (uint2*)alloc((size_t)NB * PCAP * sizeof(uint2));
    unsigned int* rpd   = (unsigned int*)alloc((size_t)N * sizeof(unsigned int));
    float* dinv         = (float*)alloc((size_t)N * sizeof(float));
    int*   cnts         = (int*)alloc((size_t)2 * NB * sizeof(int));  // ecnt | pcnt
    short* wb1          = (short*)alloc((size_t)16384 * sizeof(short));
    short* wb2          = (short*)alloc((size_t)16384 * sizeof(short));
    int* ecnt = cnts;
    int* pcnt = cnts + NB;

    // zero bucket counters (tiny)
    hipMemsetAsync(cnts, 0, (size_t)2 * NB * sizeof(int), stream);

    // single-pass bucket staging (edges + pairs) + W prepack
    stage1_kernel<<<STAGE_G, 256, 0, stream>>>(src, dst, pa, pb, ecnt, pcnt,
                                               stageE, stageP, W1, W2, wb1, wb2,
                                               E, P, NB);

    // FUSED scatter + gemm1: bucket CSR finalize + h1' = dinv*(emb@W1) -> bufA
    scatter_gemm_kernel<<<NB, 256, 0, stream>>>(stageE, ecnt, rpd, dinv,
                                                srcs_sorted, emb, wb1, (uint2*)bufA, N);

    // agg1: z1 = relu(dinv*(h1'+sum)+b1) -> bufB
    agg_kernel<<<(N + 15) / 16, 256, 0, stream>>>(bufA, rpd, srcs_sorted, dinv, b1,
                                                  bufB, N, 1);

    // gemm2: h2' = dinv*(z1@W2) -> bufA
    gemm_mfma_kernel<<<NB, 256, 0, stream>>>(bufB, wb2, dinv, (uint2*)bufA, N);

    // agg2: z2 = dinv*(h2'+sum)+b2 -> bufB
    agg_kernel<<<(N + 15) / 16, 256, 0, stream>>>(bufA, rpd, srcs_sorted, dinv, b2,
                                                  bufB, N, 0);

    // Decode: bucket-sorted pairs, A-rows from LDS, B-rows gathered (2 blocks/bucket)
    decode_bucket_kernel<<<NB * 2, 256, 0, stream>>>(bufB, stageP, pcnt, out, N);
}

// Round 4
// 211.401 us; speedup vs baseline: 1.4780x; 1.0820x over previous
//
#include <hip/hip_runtime.h>

// GCN link predictor. fp32 math, bf16 intermediates + bf16 MFMA GEMM.
// Pipeline: memset(cnts) -> stage1[hist+reserve+scatter edges&pairs + Wprepack] ->
//           FUSED[scatter+gemm1] -> agg1 -> gemm2 -> agg2 -> decode-bucket.  (7 dispatches)
// norm factorization: h'[i] = dinv[i]*(x@W)[i];  z[i] = dinv[i]*(h'[i] + sum_{src->i} h'[src]) + b.
// R5: MFMA GEMM. R6 FAILED: hot per-row global atomics. R7: deterministic bucket CSR. R8: 248us.
// R9 FAILED: grid.sync. R10: quarter-wave gathers (neutral; random-line floor ~4.5TB/s).
// R11 FAILED: agg1+gemm2 fusion cut gather parallelism. R12: fuse scatter+gemm1 (244.8us).
// R13 FAILED (312us): column-pass L2 blocking -- per-XCD reuse E/(8N)=2, can't beat LLC floor.
// R14 (254us, ~neutral): decode A-bucket halved B-gathers but refunded via random 4B touches.
// R15 (228.7us): pb embedded in pair record; 3-dispatch exact-prefix front -> 1 reserve-based
// staging dispatch. rocprof: stage1 is now the TOP dispatch (48us, occupancy 4.4%, 0.35TB/s,
// VALU 0.9%) -- latency-bound at 128 blocks x 256 thr = half the CUs idle, 1 wave/SIMD.
// R16: stage1 occupancy fix: 256 blocks x 1024 threads (16 waves/block, every CU busy).
// Reserve-atomic count stays ~200K over 782 L2 words (pipelined). W-prepack moved to blocks
// 0..7. Predict stage1 48 -> ~15us, total ~200us.

typedef __attribute__((ext_vector_type(8))) short short8;   // 8 bf16 (A/B frag)
typedef __attribute__((ext_vector_type(4))) float floatx4;  // C/D frag

#define STAGE_G 256   // staging blocks
#define STAGE_T 1024  // staging threads/block
#define ECAP 2048     // per-bucket edge capacity   (lambda~1024; overflow ~impossible, guarded)
#define PCAP 1024     // per-bucket pair capacity   (lambda~511)

__device__ __forceinline__ unsigned short f2bf(float f) {
    union { float f; unsigned int u; } v; v.f = f;
    unsigned int u = v.u;
    u += 0x7fffu + ((u >> 16) & 1u);   // round-to-nearest-even
    return (unsigned short)(u >> 16);
}

__device__ __forceinline__ unsigned int pack2(float a, float b) {
    return (unsigned int)f2bf(a) | ((unsigned int)f2bf(b) << 16);
}

__device__ __forceinline__ float4 cvt4(unsigned int lo, unsigned int hi) {
    float4 f;
    f.x = __uint_as_float(lo << 16);
    f.y = __uint_as_float(lo & 0xffff0000u);
    f.z = __uint_as_float(hi << 16);
    f.w = __uint_as_float(hi & 0xffff0000u);
    return f;
}

// --- single-pass bucket staging (edges + pairs) + W prepack ---
// Per block: LDS histogram of its chunk -> one global atomicAdd range-reserve per touched
// bucket -> LDS-cursor scatter into fixed-stride bucket regions. No exact prefix needed.
// 1024 threads/block, 256 blocks: fills all CUs (stage is random-scatter latency-bound).
__global__ __launch_bounds__(1024) void stage1_kernel(const int* __restrict__ src,
                                                      const int* __restrict__ dst,
                                                      const int* __restrict__ pa,
                                                      const int* __restrict__ pb,
                                                      int* __restrict__ ecnt,
                                                      int* __restrict__ pcnt,
                                                      unsigned int* __restrict__ stageE,
                                                      uint2* __restrict__ stageP,
                                                      const float* __restrict__ W1,
                                                      const float* __restrict__ W2,
                                                      short* __restrict__ wb1,
                                                      short* __restrict__ wb2,
                                                      int E, int P, int NB) {
    __shared__ int bh[1024];
    __shared__ int bh2[1024];
    int t = threadIdx.x, g = blockIdx.x;

    // one-time W prepack into MFMA B layout: WB[((nt*4+kt)*64+ln)*8+j]  (blocks 0..7)
    if (g < 8) {
        const float4* W4 = (const float4*)((g < 4) ? W1 : W2);
        short* wb = (g < 4) ? wb1 : wb2;
        int f = ((g & 3) * 1024) + t;          // f in [0,4096)
        int k = f >> 5;
        int c4 = f & 31;
        float4 wv = W4[f];
        int kt = k >> 5, q = (k >> 3) & 3, j = k & 7;
        float e[4] = {wv.x, wv.y, wv.z, wv.w};
#pragma unroll
        for (int m = 0; m < 4; ++m) {
            int c = c4 * 4 + m;
            int nt = c >> 4;
            int ln = q * 16 + (c & 15);
            wb[((nt * 4 + kt) * 64 + ln) * 8 + j] = (short)f2bf(e[m]);
        }
    }

    for (int b = t; b < NB; b += STAGE_T) { bh[b] = 0; bh2[b] = 0; }
    __syncthreads();

    int chunk = (E + gridDim.x - 1) / gridDim.x;
    int lo = g * chunk, hi = min(lo + chunk, E);
    int chunkP = (P + gridDim.x - 1) / gridDim.x;
    int loP = g * chunkP, hiP = min(loP + chunkP, P);

    // pass 1: count
    for (int i = lo + t; i < hi; i += STAGE_T) atomicAdd(&bh[dst[i] >> 6], 1);
    for (int i = loP + t; i < hiP; i += STAGE_T) atomicAdd(&bh2[pa[i] >> 6], 1);
    __syncthreads();

    // reserve: bh[b] becomes this block's base (local index within bucket b)
    for (int b = t; b < NB; b += STAGE_T) {
        int c = bh[b];
        if (c) bh[b] = atomicAdd(&ecnt[b], c);
        int c2 = bh2[b];
        if (c2) bh2[b] = atomicAdd(&pcnt[b], c2);
    }
    __syncthreads();

    // pass 2: scatter into strided bucket regions
    for (int i = lo + t; i < hi; i += STAGE_T) {
        int d = dst[i];
        int b = d >> 6;
        int pos = atomicAdd(&bh[b], 1);
        if (pos < ECAP)
            stageE[(b << 11) + pos] = ((unsigned int)src[i] << 6) | (unsigned int)(d & 63);
    }
    for (int i = loP + t; i < hiP; i += STAGE_T) {
        int A = pa[i];
        int b = A >> 6;
        int pos = atomicAdd(&bh2[b], 1);
        if (pos < PCAP) {
            uint2 r;
            r.x = ((unsigned int)pb[i] << 6) | (unsigned int)(A & 63);  // B < 2^26
            r.y = (unsigned int)i;
            stageP[(b << 10) + pos] = r;
        }
    }
}

// --- FUSED scatter + layer-1 GEMM. One block per bucket b == one 64-row gemm tile.
__global__ __launch_bounds__(256) void scatter_gemm_kernel(const unsigned int* __restrict__ stageE,
                                                           const int* __restrict__ ecnt,
                                                           unsigned int* __restrict__ rpd,
                                                           float* __restrict__ dinv,
                                                           int* __restrict__ srcs_sorted,
                                                           const float* __restrict__ Xv,
                                                           const short* __restrict__ wbpre,
                                                           uint2* __restrict__ H, int N) {
    __shared__ __align__(16) char smem[50176];
    __shared__ int cnt[64];
    __shared__ int lcur[64];
    __shared__ float sdinv[64];
    short* WB = (short*)smem;            // [nt][kt][lane][j]
    short* XL = (short*)(smem + 32768);  // [row][k], row stride 136 shorts
    float* Cst = (float*)smem;           // epilogue overlay: [row][col], stride 132 floats

    const int tid = threadIdx.x;
    const int blk = blockIdx.x;

    // ---- Phase 1: bucket CSR finalize ----
    {
        int t = tid;
        int lo = blk << 6;
        int base = blk << 11;            // blk*ECAP
        int cntE = ecnt[blk];
        if (t < 64) cnt[t] = 0;
        __syncthreads();
        for (int i = t; i < cntE; i += 256) atomicAdd(&cnt[stageE[base + i] & 63u], 1);
        __syncthreads();
        if (t < 64) {
            int v = cnt[t];
            int inc = v;
#pragma unroll
            for (int off = 1; off < 64; off <<= 1) {
                int x = __shfl_up(inc, off, 64);
                if (t >= off) inc += x;
            }
            int exc = inc - v;
            int node = lo + t;
            int start = base + exc;      // index into strided srcs_sorted
            float di = rsqrtf((float)(v + 1));   // +1 self-loop
            if (node < N) {
                rpd[node] = ((unsigned int)start << 7) | (unsigned int)v;  // deg < 128
                dinv[node] = di;
                sdinv[t] = di;
            } else {
                sdinv[t] = 0.f;
            }
            lcur[t] = start;
        }
        __syncthreads();
        for (int i = t; i < cntE; i += 256) {
            unsigned int rec = stageE[base + i];
            int pos = atomicAdd(&lcur[rec & 63u], 1);
            srcs_sorted[pos] = (int)(rec >> 6);
        }
    }
    __syncthreads();

    // ---- Phase 2: gemm1 (fp32 X @ W -> bf16 H, dinv from LDS) ----
    {
        const uint4* Wp = (const uint4*)wbpre;
        uint4* WB4 = (uint4*)WB;
#pragma unroll
        for (int i = 0; i < 8; ++i) {
            int idx = tid + i * 256;   // [0,2048)
            WB4[idx] = Wp[idx];
        }
    }
    {
#pragma unroll
        for (int i = 0; i < 8; ++i) {
            int f = tid + i * 256;
            int row = f >> 5;
            int c4 = f & 31;
            int gr = min(blk * 64 + row, N - 1);
            float4 xv = ((const float4*)Xv)[(size_t)gr * 32 + c4];
            uint2 u;
            u.x = pack2(xv.x, xv.y);
            u.y = pack2(xv.z, xv.w);
            *(uint2*)&XL[row * 136 + c4 * 4] = u;
        }
    }
    __syncthreads();

    const int w = tid >> 6;
    const int lane = tid & 63;
    const int arow = w * 16 + (lane & 15);
    const int koff = (lane >> 4) * 8;
    short8 a[4];
#pragma unroll
    for (int kt = 0; kt < 4; ++kt)
        a[kt] = *(const short8*)&XL[arow * 136 + kt * 32 + koff];

    floatx4 acc[8];
#pragma unroll
    for (int nt = 0; nt < 8; ++nt) acc[nt] = (floatx4){0.f, 0.f, 0.f, 0.f};

#pragma unroll
    for (int kt = 0; kt < 4; ++kt) {
#pragma unroll
        for (int nt = 0; nt < 8; ++nt) {
            short8 b = *(const short8*)&WB[((nt * 4 + kt) * 64 + lane) * 8];
            acc[nt] = __builtin_amdgcn_mfma_f32_16x16x32_bf16(a[kt], b, acc[nt], 0, 0, 0);
        }
    }
    __syncthreads();

    {
        int q = lane >> 4, cn = lane & 15;
#pragma unroll
        for (int nt = 0; nt < 8; ++nt)
#pragma unroll
            for (int r = 0; r < 4; ++r)
                Cst[(w * 16 + q * 4 + r) * 132 + nt * 16 + cn] = acc[nt][r];
    }
    __syncthreads();
    {
#pragma unroll
        for (int i = 0; i < 8; ++i) {
            int f = tid + i * 256;
            int row = f >> 5;
            int c4 = f & 31;
            int gr = blk * 64 + row;
            if (gr < N) {
                float4 v = *(float4*)&Cst[row * 132 + c4 * 4];
                float di = sdinv[row];
                uint2 o;
                o.x = pack2(v.x * di, v.y * di);
                o.y = pack2(v.z * di, v.w * di);
                H[(size_t)gr * 32 + c4] = o;
            }
        }
    }
}

// --- standalone MFMA GEMM (layer 2, bf16 input, prepacked W) ---
__global__ __launch_bounds__(256) void gemm_mfma_kernel(const unsigned short* __restrict__ Xv,
                                                        const short* __restrict__ wbpre,
                                                        const float* __restrict__ dinv,
                                                        uint2* __restrict__ H, int N) {
    __shared__ __align__(16) char smem[50176];
    short* WB = (short*)smem;
    short* XL = (short*)(smem + 32768);
    float* Cst = (float*)smem;

    const int tid = threadIdx.x;
    const int w = tid >> 6;
    const int lane = tid & 63;
    const int blk = blockIdx.x;

    {
        const uint4* Wp = (const uint4*)wbpre;
        uint4* WB4 = (uint4*)WB;
#pragma unroll
        for (int i = 0; i < 8; ++i) {
            int idx = tid + i * 256;
            WB4[idx] = Wp[idx];
        }
    }
    {
#pragma unroll
        for (int i = 0; i < 8; ++i) {
            int f = tid + i * 256;
            int row = f >> 5;
            int c4 = f & 31;
            int gr = min(blk * 64 + row, N - 1);
            uint2 u = ((const uint2*)Xv)[(size_t)gr * 32 + c4];
            *(uint2*)&XL[row * 136 + c4 * 4] = u;
        }
    }
    __syncthreads();

    const int arow = w * 16 + (lane & 15);
    const int koff = (lane >> 4) * 8;
    short8 a[4];
#pragma unroll
    for (int kt = 0; kt < 4; ++kt)
        a[kt] = *(const short8*)&XL[arow * 136 + kt * 32 + koff];

    floatx4 acc[8];
#pragma unroll
    for (int nt = 0; nt < 8; ++nt) acc[nt] = (floatx4){0.f, 0.f, 0.f, 0.f};

#pragma unroll
    for (int kt = 0; kt < 4; ++kt) {
#pragma unroll
        for (int nt = 0; nt < 8; ++nt) {
            short8 b = *(const short8*)&WB[((nt * 4 + kt) * 64 + lane) * 8];
            acc[nt] = __builtin_amdgcn_mfma_f32_16x16x32_bf16(a[kt], b, acc[nt], 0, 0, 0);
        }
    }
    __syncthreads();

    {
        int q = lane >> 4, cn = lane & 15;
#pragma unroll
        for (int nt = 0; nt < 8; ++nt)
#pragma unroll
            for (int r = 0; r < 4; ++r)
                Cst[(w * 16 + q * 4 + r) * 132 + nt * 16 + cn] = acc[nt][r];
    }
    __syncthreads();
    {
#pragma unroll
        for (int i = 0; i < 8; ++i) {
            int f = tid + i * 256;
            int row = f >> 5;
            int c4 = f & 31;
            int gr = blk * 64 + row;
            if (gr < N) {
                float4 v = *(float4*)&Cst[row * 132 + c4 * 4];
                float di = dinv[gr];
                uint2 o;
                o.x = pack2(v.x * di, v.y * di);
                o.y = pack2(v.z * di, v.w * di);
                H[(size_t)gr * 32 + c4] = o;
            }
        }
    }
}

// Quarter-wave (16 lanes) per node; lane holds 8 cols as uint4. fp32 accumulate.
// rpd[n] = (start<<7)|deg into strided srcs (deg < 128, Poisson-16: safe).
__global__ __launch_bounds__(256) void agg_kernel(const unsigned short* __restrict__ Hp,
                                                  const unsigned int* __restrict__ rpd,
                                                  const int* __restrict__ srcs,
                                                  const float* __restrict__ dinv,
                                                  const float* __restrict__ bias,
                                                  unsigned short* __restrict__ Z,
                                                  int N, int do_relu) {
    int gw = (int)((blockIdx.x * blockDim.x + threadIdx.x) >> 6);
    int lane = threadIdx.x & 63;
    int q = lane >> 4;
    int hl = lane & 15;
    int n = gw * 4 + q;
    if (n >= N) return;

    const uint4* H4 = (const uint4*)Hp;
    uint4 us = H4[(size_t)n * 16 + hl];
    float4 a0 = cvt4(us.x, us.y);
    float4 a1 = cvt4(us.z, us.w);
    float4 b0 = make_float4(0.f, 0.f, 0.f, 0.f);
    float4 b1 = make_float4(0.f, 0.f, 0.f, 0.f);

    unsigned int rp = rpd[n];
    int j = (int)(rp >> 7), end = j + (int)(rp & 127u);
    for (; j + 7 < end; j += 8) {
        uint4 u0 = H4[(size_t)srcs[j + 0] * 16 + hl];
        uint4 u1 = H4[(size_t)srcs[j + 1] * 16 + hl];
        uint4 u2 = H4[(size_t)srcs[j + 2] * 16 + hl];
        uint4 u3 = H4[(size_t)srcs[j + 3] * 16 + hl];
        uint4 u4 = H4[(size_t)srcs[j + 4] * 16 + hl];
        uint4 u5 = H4[(size_t)srcs[j + 5] * 16 + hl];
        uint4 u6 = H4[(size_t)srcs[j + 6] * 16 + hl];
        uint4 u7 = H4[(size_t)srcs[j + 7] * 16 + hl];
        float4 t;
        t = cvt4(u0.x, u0.y); a0.x += t.x; a0.y += t.y; a0.z += t.z; a0.w += t.w;
        t = cvt4(u0.z, u0.w); a1.x += t.x; a1.y += t.y; a1.z += t.z; a1.w += t.w;
        t = cvt4(u1.x, u1.y); b0.x += t.x; b0.y += t.y; b0.z += t.z; b0.w += t.w;
        t = cvt4(u1.z, u1.w); b1.x += t.x; b1.y += t.y; b1.z += t.z; b1.w += t.w;
        t = cvt4(u2.x, u2.y); a0.x += t.x; a0.y += t.y; a0.z += t.z; a0.w += t.w;
        t = cvt4(u2.z, u2.w); a1.x += t.x; a1.y += t.y; a1.z += t.z; a1.w += t.w;
        t = cvt4(u3.x, u3.y); b0.x += t.x; b0.y += t.y; b0.z += t.z; b0.w += t.w;
        t = cvt4(u3.z, u3.w); b1.x += t.x; b1.y += t.y; b1.z += t.z; b1.w += t.w;
        t = cvt4(u4.x, u4.y); a0.x += t.x; a0.y += t.y; a0.z += t.z; a0.w += t.w;
        t = cvt4(u4.z, u4.w); a1.x += t.x; a1.y += t.y; a1.z += t.z; a1.w += t.w;
        t = cvt4(u5.x, u5.y); b0.x += t.x; b0.y += t.y; b0.z += t.z; b0.w += t.w;
        t = cvt4(u5.z, u5.w); b1.x += t.x; b1.y += t.y; b1.z += t.z; b1.w += t.w;
        t = cvt4(u6.x, u6.y); a0.x += t.x; a0.y += t.y; a0.z += t.z; a0.w += t.w;
        t = cvt4(u6.z, u6.w); a1.x += t.x; a1.y += t.y; a1.z += t.z; a1.w += t.w;
        t = cvt4(u7.x, u7.y); b0.x += t.x; b0.y += t.y; b0.z += t.z; b0.w += t.w;
        t = cvt4(u7.z, u7.w); b1.x += t.x; b1.y += t.y; b1.z += t.z; b1.w += t.w;
    }
    for (; j + 3 < end; j += 4) {
        uint4 u0 = H4[(size_t)srcs[j + 0] * 16 + hl];
        uint4 u1 = H4[(size_t)srcs[j + 1] * 16 + hl];
        uint4 u2 = H4[(size_t)srcs[j + 2] * 16 + hl];
        uint4 u3 = H4[(size_t)srcs[j + 3] * 16 + hl];
        float4 t;
        t = cvt4(u0.x, u0.y); a0.x += t.x; a0.y += t.y; a0.z += t.z; a0.w += t.w;
        t = cvt4(u0.z, u0.w); a1.x += t.x; a1.y += t.y; a1.z += t.z; a1.w += t.w;
        t = cvt4(u1.x, u1.y); b0.x += t.x; b0.y += t.y; b0.z += t.z; b0.w += t.w;
        t = cvt4(u1.z, u1.w); b1.x += t.x; b1.y += t.y; b1.z += t.z; b1.w += t.w;
        t = cvt4(u2.x, u2.y); a0.x += t.x; a0.y += t.y; a0.z += t.z; a0.w += t.w;
        t = cvt4(u2.z, u2.w); a1.x += t.x; a1.y += t.y; a1.z += t.z; a1.w += t.w;
        t = cvt4(u3.x, u3.y); b0.x += t.x; b0.y += t.y; b0.z += t.z; b0.w += t.w;
        t = cvt4(u3.z, u3.w); b1.x += t.x; b1.y += t.y; b1.z += t.z; b1.w += t.w;
    }
    for (; j < end; ++j) {
        uint4 u = H4[(size_t)srcs[j] * 16 + hl];
        float4 t;
        t = cvt4(u.x, u.y); a0.x += t.x; a0.y += t.y; a0.z += t.z; a0.w += t.w;
        t = cvt4(u.z, u.w); a1.x += t.x; a1.y += t.y; a1.z += t.z; a1.w += t.w;
    }
    a0.x += b0.x; a0.y += b0.y; a0.z += b0.z; a0.w += b0.w;
    a1.x += b1.x; a1.y += b1.y; a1.z += b1.z; a1.w += b1.w;

    float di = dinv[n];
    float4 bv0 = ((const float4*)bias)[2 * hl];
    float4 bv1 = ((const float4*)bias)[2 * hl + 1];
    float o0 = di * a0.x + bv0.x, o1 = di * a0.y + bv0.y;
    float o2 = di * a0.z + bv0.z, o3 = di * a0.w + bv0.w;
    float o4 = di * a1.x + bv1.x, o5 = di * a1.y + bv1.y;
    float o6 = di * a1.z + bv1.z, o7 = di * a1.w + bv1.w;
    if (do_relu) {
        o0 = fmaxf(o0, 0.f); o1 = fmaxf(o1, 0.f); o2 = fmaxf(o2, 0.f); o3 = fmaxf(o3, 0.f);
        o4 = fmaxf(o4, 0.f); o5 = fmaxf(o5, 0.f); o6 = fmaxf(o6, 0.f); o7 = fmaxf(o7, 0.f);
    }
    uint4 o;
    o.x = pack2(o0, o1);
    o.y = pack2(o2, o3);
    o.z = pack2(o4, o5);
    o.w = pack2(o6, o7);
    ((uint4*)Z)[(size_t)n * 16 + hl] = o;
}

// Decode: pairs bucket-sorted by A, B index embedded in the record (no random pb read).
// 2 blocks per bucket; block stages the bucket's 64 A-rows (16KB) in LDS; 16-lane groups
// process 4 pairs in flight: A from LDS + B random row-gather. out[pidx] random 4B write.
__global__ __launch_bounds__(256) void decode_bucket_kernel(const unsigned short* __restrict__ Zp,
                                                            const uint2* __restrict__ stageP,
                                                            const int* __restrict__ pcnt,
                                                            float* __restrict__ out,
                                                            int N) {
    __shared__ __align__(16) short AL[64 * 136];
    const int tid = threadIdx.x;
    const int blk = blockIdx.x >> 1;
    const int half = blockIdx.x & 1;
    const uint2* SP = stageP + ((size_t)blk << 10);   // blk*PCAP
    const uint4* Z4 = (const uint4*)Zp;

    // stage A rows (coalesced; rows beyond N clamp to N-1, never referenced by pairs)
#pragma unroll
    for (int i = 0; i < 4; ++i) {
        int idx = tid + i * 256;        // [0,1024)
        int row = idx >> 4, hl = idx & 15;
        int gr = min(blk * 64 + row, N - 1);
        *(uint4*)&AL[row * 136 + hl * 8] = Z4[(size_t)gr * 16 + hl];
    }
    __syncthreads();

    int cntP = pcnt[blk];
    int gp = half * 16 + (tid >> 4);    // group id in [0,32)
    int hl = tid & 15;

    for (int k = gp; k < cntP; k += 128) {
        int i1 = k + 32, i2 = k + 64, i3 = k + 96;
        bool h1 = i1 < cntP, h2 = i2 < cntP, h3 = i3 < cntP;
        uint2 r0 = SP[k];
        uint2 r1 = h1 ? SP[i1] : r0;
        uint2 r2 = h2 ? SP[i2] : r0;
        uint2 r3 = h3 ? SP[i3] : r0;
        int B0 = (int)(r0.x >> 6), B1 = (int)(r1.x >> 6);
        int B2 = (int)(r2.x >> 6), B3 = (int)(r3.x >> 6);
        uint4 ub0 = Z4[(size_t)B0 * 16 + hl];
        uint4 ub1 = Z4[(size_t)B1 * 16 + hl];
        uint4 ub2 = Z4[(size_t)B2 * 16 + hl];
        uint4 ub3 = Z4[(size_t)B3 * 16 + hl];
        uint4 ua0 = *(const uint4*)&AL[(int)(r0.x & 63u) * 136 + hl * 8];
        uint4 ua1 = *(const uint4*)&AL[(int)(r1.x & 63u) * 136 + hl * 8];
        uint4 ua2 = *(const uint4*)&AL[(int)(r2.x & 63u) * 136 + hl * 8];
        uint4 ua3 = *(const uint4*)&AL[(int)(r3.x & 63u) * 136 + hl * 8];

        float4 xa, xb, ya, yb;
        xa = cvt4(ua0.x, ua0.y); xb = cvt4(ub0.x, ub0.y);
        ya = cvt4(ua0.z, ua0.w); yb = cvt4(ub0.z, ub0.w);
        float v0 = xa.x * xb.x + xa.y * xb.y + xa.z * xb.z + xa.w * xb.w
                 + ya.x * yb.x + ya.y * yb.y + ya.z * yb.z + ya.w * yb.w;
        xa = cvt4(ua1.x, ua1.y); xb = cvt4(ub1.x, ub1.y);
        ya = cvt4(ua1.z, ua1.w); yb = cvt4(ub1.z, ub1.w);
        float v1 = xa.x * xb.x + xa.y * xb.y + xa.z * xb.z + xa.w * xb.w
                 + ya.x * yb.x + ya.y * yb.y + ya.z * yb.z + ya.w * yb.w;
        xa = cvt4(ua2.x, ua2.y); xb = cvt4(ub2.x, ub2.y);
        ya = cvt4(ua2.z, ua2.w); yb = cvt4(ub2.z, ub2.w);
        float v2 = xa.x * xb.x + xa.y * xb.y + xa.z * xb.z + xa.w * xb.w
                 + ya.x * yb.x + ya.y * yb.y + ya.z * yb.z + ya.w * yb.w;
        xa = cvt4(ua3.x, ua3.y); xb = cvt4(ub3.x, ub3.y);
        ya = cvt4(ua3.z, ua3.w); yb = cvt4(ub3.z, ub3.w);
        float v3 = xa.x * xb.x + xa.y * xb.y + xa.z * xb.z + xa.w * xb.w
                 + ya.x * yb.x + ya.y * yb.y + ya.z * yb.z + ya.w * yb.w;
#pragma unroll
        for (int off = 8; off > 0; off >>= 1) {
            v0 += __shfl_down(v0, off, 16);
            v1 += __shfl_down(v1, off, 16);
            v2 += __shfl_down(v2, off, 16);
            v3 += __shfl_down(v3, off, 16);
        }
        if (hl == 0) {
            out[r0.y] = v0;
            if (h1) out[r1.y] = v1;
            if (h2) out[r2.y] = v2;
            if (h3) out[r3.y] = v3;
        }
    }
}

extern "C" void kernel_launch(void* const* d_in, const int* in_sizes, int n_in,
                              void* d_out, int out_size, void* d_ws, size_t ws_size,
                              hipStream_t stream) {
    const int*   edge_index = (const int*)d_in[0];
    const int*   edge_pairs = (const int*)d_in[1];
    const float* emb        = (const float*)d_in[2];
    const float* W1         = (const float*)d_in[3];
    const float* b1         = (const float*)d_in[4];
    const float* W2         = (const float*)d_in[5];
    const float* b2         = (const float*)d_in[6];
    float* out = (float*)d_out;

    int E = in_sizes[0] / 2;
    int P = in_sizes[1] / 2;
    int N = in_sizes[2] / 128;
    int NB = (N + 63) / 64;    // buckets == gemm tiles (782 for N=50000; must be <= 1024)

    const int* src = edge_index;
    const int* dst = edge_index + E;
    const int* pa  = edge_pairs;
    const int* pb  = edge_pairs + P;

    char* ws = (char*)d_ws;
    size_t off = 0;
    auto alloc = [&](size_t bytes) -> void* {
        void* p = ws + off;
        off = (off + bytes + 255) & ~(size_t)255;
        return p;
    };
    unsigned short* bufA = (unsigned short*)alloc((size_t)N * 128 * 2); // h1' then h2'
    unsigned short* bufB = (unsigned short*)alloc((size_t)N * 128 * 2); // z1 then z2
    int*   srcs_sorted  = (int*)alloc((size_t)NB * ECAP * sizeof(int));
    unsigned int* stageE = (unsigned int*)alloc((size_t)NB * ECAP * sizeof(unsigned int));
    uint2* stageP       = (uint2*)alloc((size_t)NB * PCAP * sizeof(uint2));
    unsigned int* rpd   = (unsigned int*)alloc((size_t)N * sizeof(unsigned int));
    float* dinv         = (float*)alloc((size_t)N * sizeof(float));
    int*   cnts         = (int*)alloc((size_t)2 * NB * sizeof(int));  // ecnt | pcnt
    short* wb1          = (short*)alloc((size_t)16384 * sizeof(short));
    short* wb2          = (short*)alloc((size_t)16384 * sizeof(short));
    int* ecnt = cnts;
    int* pcnt = cnts + NB;

    // zero bucket counters (tiny)
    hipMemsetAsync(cnts, 0, (size_t)2 * NB * sizeof(int), stream);

    // single-pass bucket staging (edges + pairs) + W prepack; full-occupancy launch
    stage1_kernel<<<STAGE_G, STAGE_T, 0, stream>>>(src, dst, pa, pb, ecnt, pcnt,
                                                   stageE, stageP, W1, W2, wb1, wb2,
                                                   E, P, NB);

    // FUSED scatter + gemm1: bucket CSR finalize + h1' = dinv*(emb@W1) -> bufA
    scatter_gemm_kernel<<<NB, 256, 0, stream>>>(stageE, ecnt, rpd, dinv,
                                                srcs_sorted, emb, wb1, (uint2*)bufA, N);

    // agg1: z1 = relu(dinv*(h1'+sum)+b1) -> bufB
    agg_kernel<<<(N + 15) / 16, 256, 0, stream>>>(bufA, rpd, srcs_sorted, dinv, b1,
                                                  bufB, N, 1);

    // gemm2: h2' = dinv*(z1@W2) -> bufA
    gemm_mfma_kernel<<<NB, 256, 0, stream>>>(bufB, wb2, dinv, (uint2*)bufA, N);

    // agg2: z2 = dinv*(h2'+sum)+b2 -> bufB
    agg_kernel<<<(N + 15) / 16, 256, 0, stream>>>(bufA, rpd, srcs_sorted, dinv, b2,
                                                  bufB, N, 0);

    // Decode: bucket-sorted pairs, A-rows from LDS, B-rows gathered (2 blocks/bucket)
    decode_bucket_kernel<<<NB * 2, 256, 0, stream>>>(bufB, stageP, pcnt, out, N);
}